// Round 1
// baseline (603.913 us; speedup 1.0000x reference)
//
#include <hip/hip_runtime.h>
#include <math.h>

#define EPS_BN 1e-5f

// Problem constants: B=32, NS=200, NQ=100, C=8, L=512, H=32, F=128, N_WAY=20
#define NSUP   6400
#define NQRY   3200
#define NSAMP  9600
#define NWAY   20
#define NSHOTB 200
#define NQB    100

using short8  = __attribute__((ext_vector_type(8))) short;
using floatx4 = __attribute__((ext_vector_type(4))) float;

// accurate split (prep only): RNE both halves
__device__ __forceinline__ void bf16_split_rn(float x, unsigned& uh, unsigned& ul) {
    unsigned u = __float_as_uint(x);
    uh = (u + 0x7FFFu + ((u >> 16) & 1u)) >> 16;
    float e = x - __uint_as_float(uh << 16);
    unsigned ue = __float_as_uint(e);
    ul = (ue + 0x7FFFu + ((ue >> 16) & 1u)) >> 16;
}
// fast split (hot path): RNE hi, truncated lo
__device__ __forceinline__ void bf16_split_fast(float x, unsigned& uh, unsigned& ul) {
    unsigned u = __float_as_uint(x);
    uh = (u + 0x7FFFu + ((u >> 16) & 1u)) >> 16;
    float e = x - __uint_as_float(uh << 16);
    ul = __float_as_uint(e) >> 16;
}

// ===========================================================================
// prep: W1 [32][8][3], W2 [64][32][3], W3 [128][64][3] -> MFMA B-fragment
// order, split hi/lo bf16 (layouts verified rounds 4-8).
//  W1: frag=nt*2+hl; co=nt*16+(lane&15), k=quad*8+j -> t=quad, ci=j; t==3 -> 0
// ===========================================================================
__global__ __launch_bounds__(256) void prep_weights(
    const float* __restrict__ w1, const float* __restrict__ w2,
    const float* __restrict__ w3, unsigned short* __restrict__ Wf1,
    unsigned short* __restrict__ Wf2, unsigned short* __restrict__ Wf3)
{
    int b = blockIdx.x;
    if (b < 24) {                         // W2: 24 frags x 512
        int e = b * 512 + threadIdx.x;
        #pragma unroll
        for (int r = 0; r < 2; ++r, e += 256) {
            int frag = e >> 9, off = e & 511;
            int lane = off >> 3, j = off & 7;
            int hl = frag & 1, f2 = frag >> 1;
            int nt = f2 & 3, t = f2 >> 2;
            int co = nt * 16 + (lane & 15);
            int ci = (lane >> 4) * 8 + j;
            float x = w2[(co * 32 + ci) * 3 + t];
            unsigned uh, ul; bf16_split_rn(x, uh, ul);
            Wf2[e] = (unsigned short)(hl ? ul : uh);
        }
    } else if (b < 120) {                 // W3: 96 frags x 512
        int e = (b - 24) * 512 + threadIdx.x;
        #pragma unroll
        for (int r = 0; r < 2; ++r, e += 256) {
            int frag = e >> 9, off = e & 511;
            int lane = off >> 3, j = off & 7;
            int hl = frag & 1, f2 = frag >> 1;
            int nt = f2 & 7, f3 = f2 >> 3;
            int ks = f3 & 1, t = f3 >> 1;
            int co = nt * 16 + (lane & 15);
            int ci = ks * 32 + (lane >> 4) * 8 + j;
            float x = w3[(co * 64 + ci) * 3 + t];
            unsigned uh, ul; bf16_split_rn(x, uh, ul);
            Wf3[e] = (unsigned short)(hl ? ul : uh);
        }
    } else {                              // W1: 4 frags x 512
        int e = (b - 120) * 512 + threadIdx.x;
        #pragma unroll
        for (int r = 0; r < 2; ++r, e += 256) {
            int frag = e >> 9, off = e & 511;
            int lane = off >> 3, j = off & 7;
            int hl = frag & 1, nt = frag >> 1;
            int co = nt * 16 + (lane & 15);
            int t  = lane >> 4;           // quad = tap (K = t*8+ci)
            float x = (t < 3) ? w1[(co * 8 + j) * 3 + t] : 0.f;
            unsigned uh, ul; bf16_split_rn(x, uh, ul);
            Wf1[e] = (unsigned short)(hl ? ul : uh);
        }
    }
}

// ===========================================================================
// Fused encoder. Occupancy-targeted restructure (4 blocks/CU):
//  - LDS 51.4K -> 39.2K: B1 stride 40->32 shorts (b128 alignment kept),
//    conv1 runs in 4 quarters of 128 pre-pool rows (Xt = 132 rows only).
//  - Register budget <=128 combined: conv3 2-pass over nt-halves (acc 32),
//    conv2 loads W per nt-pair (W regs 16). Extra ds_read_b128s are cheap.
//  - conv1 next-quarter inputs prefetched to registers before each MFMA
//    sweep (hides HBM latency under MFMA).
//  - conv1 drops the Al*Wl term (4->3 terms, error ~2^-18).
//  - tail: featr kept in registers, L2-norm via shuffle reduce.
// ===========================================================================
__global__ __launch_bounds__(256, 4) void encoder_fused(
    const float* __restrict__ s_img, const float* __restrict__ q_img,
    const unsigned short* __restrict__ Wf1,
    const float* __restrict__ pb1, const float* __restrict__ pg1,
    const float* __restrict__ pbe1, const float* __restrict__ pm1,
    const float* __restrict__ pv1,
    const float* __restrict__ pb2, const float* __restrict__ pg2,
    const float* __restrict__ pbe2, const float* __restrict__ pm2,
    const float* __restrict__ pv2, const unsigned short* __restrict__ Wf2,
    const float* __restrict__ pb3, const float* __restrict__ pg3,
    const float* __restrict__ pbe3, const float* __restrict__ pm3,
    const float* __restrict__ pv3, const unsigned short* __restrict__ Wf3,
    const float* __restrict__ pwf, const float* __restrict__ pbf,
    const float* __restrict__ pgf, const float* __restrict__ pbef,
    const float* __restrict__ pmf, const float* __restrict__ pvf,
    float* __restrict__ feat_out)
{
    // U regions (time-multiplexed), total 37440 B:
    //  conv1/conv2: B1h @0 (16512), B1l @16512 (16512),
    //               Xth @33024 (132 rows x 16 B = 2112), Xtl @35136 (2112)
    //  conv3:       X2h @0 (18720), X2l @18720 (18720)
    //  tail:        part @0 (1024), featm @1024 (512)
    __shared__ __align__(16) char U[37440];
    short* const B1h = (short*)U;
    short* const B1l = (short*)(U + 16512);
    short* const Xth = (short*)(U + 33024);
    short* const Xtl = (short*)(U + 35136);
    short* const X2h = (short*)U;
    short* const X2l = (short*)(U + 18720);
    float* const part  = (float*)U;             // [2][128]
    float* const featm = (float*)(U + 1024);    // [128]
    __shared__ float sc1[32], sh1[32], sc2[64], sh2[64], sc3[128], sh3[128];

    const int tid  = threadIdx.x;
    const int sid  = blockIdx.x;
    const int lane = tid & 63;
    const int wid  = tid >> 6;
    const int mrow = lane & 15;
    const int quad = lane >> 4;
    const int kq   = quad * 8;

    const float* xin = (sid < NSUP) ? (s_img + (size_t)sid * 4096)
                                    : (q_img + (size_t)(sid - NSUP) * 4096);

    // ---- init: fold BN params, zero B1 halo rows ----
    if (tid < 32) {
        float s = pg1[tid] * rsqrtf(pv1[tid] + EPS_BN);
        sc1[tid] = s; sh1[tid] = (pb1[tid] - pm1[tid]) * s + pbe1[tid];
    } else if (tid < 96) {
        int c = tid - 32;
        float s = pg2[c] * rsqrtf(pv2[c] + EPS_BN);
        sc2[c] = s; sh2[c] = (pb2[c] - pm2[c]) * s + pbe2[c];
    } else if (tid < 224) {
        int c = tid - 96;
        float s = pg3[c] * rsqrtf(pv3[c] + EPS_BN);
        sc3[c] = s; sh3[c] = (pb3[c] - pm3[c]) * s + pbe3[c];
    }
    if (tid < 32) {  // B1 halo rows 0, 257 (epilogues never write them)
        B1h[tid] = 0; B1l[tid] = 0;
        B1h[257*32 + tid] = 0; B1l[257*32 + tid] = 0;
    }
    // preload conv1 W fragments (persist in VGPRs)
    short8 W1h[2], W1l[2];
    #pragma unroll
    for (int nt = 0; nt < 2; ++nt) {
        W1h[nt] = *(const short8*)(Wf1 + ((nt*2 + 0)*512 + lane*8));
        W1l[nt] = *(const short8*)(Wf1 + ((nt*2 + 1)*512 + lane*8));
    }

    // ---- conv1: 4 quarters of 128 pre-pool rows; register prefetch ----
    const bool bld = (tid <= 130);   // Xt rows 0..130 (row r <-> l = q*128+r-1)
    float xr[8];
    {
        const int l0 = tid - 1;      // q=0; l<512 automatic
        #pragma unroll
        for (int ci = 0; ci < 8; ++ci)
            xr[ci] = (bld && l0 >= 0) ? xin[ci*512 + l0] : 0.f;
    }
    for (int q = 0; q < 4; ++q) {
        if (bld) {
            short8 vh, vl;
            #pragma unroll
            for (int ci = 0; ci < 8; ++ci) {
                unsigned uh, ul; bf16_split_fast(xr[ci], uh, ul);
                vh[ci] = (short)uh; vl[ci] = (short)ul;
            }
            *(short8*)&Xth[tid*8] = vh;
            *(short8*)&Xtl[tid*8] = vl;
        }
        __syncthreads();
        if (q < 3) {                 // prefetch next quarter under the MFMA sweep
            const int l = (q+1)*128 + tid - 1;   // >=127, only upper bound needed
            #pragma unroll
            for (int ci = 0; ci < 8; ++ci)
                xr[ci] = (bld && l < 512) ? xin[ci*512 + l] : 0.f;
        }
        // MFMA sweep: wave owns mt_local {2w, 2w+1}; A-frag = one b128/row
        #pragma unroll
        for (int mi = 0; mi < 2; ++mi) {
            const int mtl = wid*2 + mi;
            const int mt  = q*8 + mtl;
            const int row = mtl*16 + mrow + quad;
            const short8 Ah = *(const short8*)&Xth[row*8];
            const short8 Al = *(const short8*)&Xtl[row*8];
            floatx4 a1[2] = {};
            #pragma unroll
            for (int nt = 0; nt < 2; ++nt) {
                a1[nt] = __builtin_amdgcn_mfma_f32_16x16x32_bf16(Ah, W1h[nt], a1[nt], 0, 0, 0);
                a1[nt] = __builtin_amdgcn_mfma_f32_16x16x32_bf16(Ah, W1l[nt], a1[nt], 0, 0, 0);
                a1[nt] = __builtin_amdgcn_mfma_f32_16x16x32_bf16(Al, W1h[nt], a1[nt], 0, 0, 0);
            }
            // epilogue: BN+ReLU+pool2 -> B1 rows (stride 32)
            const int pl0 = mt*8 + quad*2 + 1;   // +1 halo
            #pragma unroll
            for (int nt = 0; nt < 2; ++nt) {
                const int co = nt*16 + mrow;
                const float sc = sc1[co], sh = sh1[co];
                floatx4 d = a1[nt];
                float v0 = fmaxf(0.f, fmaxf(d[0]*sc + sh, d[1]*sc + sh));
                float v1 = fmaxf(0.f, fmaxf(d[2]*sc + sh, d[3]*sc + sh));
                unsigned uh, ul;
                bf16_split_fast(v0, uh, ul);
                B1h[pl0*32 + co] = (short)uh; B1l[pl0*32 + co] = (short)ul;
                bf16_split_fast(v1, uh, ul);
                B1h[(pl0+1)*32 + co] = (short)uh; B1l[(pl0+1)*32 + co] = (short)ul;
            }
        }
        __syncthreads();   // protect Xt for next quarter / B1 complete for conv2
    }

    // ---- conv2 MFMA: M=256, N=64, K=32, 3 taps, 3-term.
    // Wave w owns mt {4w..4w+3} x ALL nt; W loaded per nt-pair (16 regs).
    floatx4 acc2[4][4] = {};
    for (int t = 0; t < 3; ++t) {
        #pragma unroll
        for (int nh = 0; nh < 2; ++nh) {
            short8 W2h[2], W2l[2];
            #pragma unroll
            for (int n = 0; n < 2; ++n) {
                const int nt = nh*2 + n;
                W2h[n] = *(const short8*)(Wf2 + (((t*4 + nt)*2 + 0)*512 + lane*8));
                W2l[n] = *(const short8*)(Wf2 + (((t*4 + nt)*2 + 1)*512 + lane*8));
            }
            #pragma unroll
            for (int mi = 0; mi < 4; ++mi) {
                const int mt = wid*4 + mi;
                const int base = (mt*16 + mrow + t)*32 + kq;
                const short8 Ah = *(const short8*)&B1h[base];
                const short8 Al = *(const short8*)&B1l[base];
                #pragma unroll
                for (int n = 0; n < 2; ++n) {
                    const int nt = nh*2 + n;
                    acc2[mi][nt] = __builtin_amdgcn_mfma_f32_16x16x32_bf16(Ah, W2h[n], acc2[mi][nt], 0, 0, 0);
                    acc2[mi][nt] = __builtin_amdgcn_mfma_f32_16x16x32_bf16(Ah, W2l[n], acc2[mi][nt], 0, 0, 0);
                    acc2[mi][nt] = __builtin_amdgcn_mfma_f32_16x16x32_bf16(Al, W2h[n], acc2[mi][nt], 0, 0, 0);
                }
            }
        }
    }
    __syncthreads();   // B1 dead

    // ---- conv2 epilogue -> X2 (BN+ReLU+pool2, split bf16) ----
    {
        #pragma unroll
        for (int mi = 0; mi < 4; ++mi) {
            const int mt = wid*4 + mi;
            const int r0 = mt*8 + quad*2 + 1;
            #pragma unroll
            for (int nt = 0; nt < 4; ++nt) {
                const int co = nt*16 + mrow;
                const float sc = sc2[co], sh = sh2[co];
                floatx4 d = acc2[mi][nt];
                float v0 = fmaxf(0.f, fmaxf(d[0]*sc + sh, d[1]*sc + sh));
                float v1 = fmaxf(0.f, fmaxf(d[2]*sc + sh, d[3]*sc + sh));
                unsigned uh, ul;
                bf16_split_fast(v0, uh, ul);
                X2h[r0*72 + co] = (short)uh; X2l[r0*72 + co] = (short)ul;
                bf16_split_fast(v1, uh, ul);
                X2h[(r0+1)*72 + co] = (short)uh; X2l[(r0+1)*72 + co] = (short)ul;
            }
        }
        if (tid < 72) {
            X2h[tid] = 0; X2l[tid] = 0;
            X2h[129*72 + tid] = 0; X2l[129*72 + tid] = 0;
        }
    }
    __syncthreads();

    // ---- conv3 MFMA: M=128, N=128, K=64, 3 taps, 3-term.
    // Wave w: mt {(w&1)*4..+3} x nt {(w>>1)*4..+3}; 2 passes over nt-halves
    // (acc 32 regs/pass); per-pass fold into s4 registers (no LDS writes).
    const int mt0 = (wid & 1) * 4;
    const int ntb = (wid >> 1) * 4;
    float s4[4];
    #pragma unroll
    for (int nh = 0; nh < 2; ++nh) {
        floatx4 acc3[4][2] = {};
        for (int t = 0; t < 3; ++t) {
            #pragma unroll
            for (int ks = 0; ks < 2; ++ks) {
                const int fb = (t*2 + ks) * 8;
                short8 W3h[2], W3l[2];
                #pragma unroll
                for (int n = 0; n < 2; ++n) {
                    const int nt = ntb + nh*2 + n;
                    W3h[n] = *(const short8*)(Wf3 + (((fb + nt)*2 + 0)*512 + lane*8));
                    W3l[n] = *(const short8*)(Wf3 + (((fb + nt)*2 + 1)*512 + lane*8));
                }
                #pragma unroll
                for (int mi = 0; mi < 4; ++mi) {
                    const int base = ((mt0 + mi)*16 + mrow + t)*72 + ks*32 + kq;
                    const short8 Ah = *(const short8*)&X2h[base];
                    const short8 Al = *(const short8*)&X2l[base];
                    #pragma unroll
                    for (int n = 0; n < 2; ++n) {
                        acc3[mi][n] = __builtin_amdgcn_mfma_f32_16x16x32_bf16(Ah, W3h[n], acc3[mi][n], 0, 0, 0);
                        acc3[mi][n] = __builtin_amdgcn_mfma_f32_16x16x32_bf16(Ah, W3l[n], acc3[mi][n], 0, 0, 0);
                        acc3[mi][n] = __builtin_amdgcn_mfma_f32_16x16x32_bf16(Al, W3h[n], acc3[mi][n], 0, 0, 0);
                    }
                }
            }
        }
        // fold this nt-half: BN+ReLU+pool2+sum over positions -> registers
        #pragma unroll
        for (int n = 0; n < 2; ++n) {
            const int j = nh*2 + n;
            const int co = (ntb + j)*16 + mrow;
            const float sc = sc3[co], sh = sh3[co];
            float s = 0.f;
            #pragma unroll
            for (int mi = 0; mi < 4; ++mi) {
                floatx4 d = acc3[mi][n];
                s += fmaxf(0.f, fmaxf(d[0]*sc + sh, d[1]*sc + sh));
                s += fmaxf(0.f, fmaxf(d[2]*sc + sh, d[3]*sc + sh));
            }
            s4[j] = s;
        }
    }
    __syncthreads();   // all X2 reads done; tail arrays live at U base

    // ---- conv3 reduction: 2-wave partials ----
    #pragma unroll
    for (int n = 0; n < 4; ++n) {
        s4[n] += __shfl_xor(s4[n], 16);
        s4[n] += __shfl_xor(s4[n], 32);
    }
    if (lane < 16) {
        #pragma unroll
        for (int n = 0; n < 4; ++n)
            part[(wid & 1)*128 + (ntb + n)*16 + lane] = s4[n];
    }
    __syncthreads();
    if (tid < 128) featm[tid] = (part[tid] + part[128 + tid]) * (1.0f / 64.0f);
    __syncthreads();

    // ---- linear 128->128 + BN + ReLU (register result) + L2 normalize ----
    float vout = 0.f;
    if (tid < 128) {
        const float* wr = pwf + (size_t)tid * 128;
        float s = 0.f;
        #pragma unroll 4
        for (int i = 0; i < 128; i += 4) {
            float4 w4 = *(const float4*)(wr + i);
            s += w4.x*featm[i] + w4.y*featm[i+1] + w4.z*featm[i+2] + w4.w*featm[i+3];
        }
        s += pbf[tid];
        s = (s - pmf[tid]) * (pgf[tid] * rsqrtf(pvf[tid] + EPS_BN)) + pbef[tid];
        vout = fmaxf(s, 0.f);
        float ss = vout * vout;
        ss += __shfl_xor(ss, 1);
        ss += __shfl_xor(ss, 2);
        ss += __shfl_xor(ss, 4);
        ss += __shfl_xor(ss, 8);
        ss += __shfl_xor(ss, 16);
        ss += __shfl_xor(ss, 32);
        if (lane == 0) part[wid] = ss;   // wid 0,1
    }
    __syncthreads();
    if (tid < 128) {
        float n = fmaxf(sqrtf(part[0] + part[1]), 1e-12f);
        feat_out[(size_t)sid * 128 + tid] = vout / n;
    }
}

// ---------------------------------------------------------------------------
// proto: stage labels in LDS, unconditional coalesced feature loads with
// predicated accumulate (no 200-deep dependent global-load chain).
__global__ __launch_bounds__(128) void proto_kernel(
    const float* __restrict__ feat_s, const int* __restrict__ s_lab,
    float* __restrict__ protos)
{
    __shared__ int labL[NSHOTB];
    const int b = blockIdx.x / NWAY;
    const int w = blockIdx.x % NWAY;
    const int f = threadIdx.x;
    const int* lab = s_lab + b * NSHOTB;
    for (int s = f; s < NSHOTB; s += 128) labL[s] = lab[s];
    __syncthreads();
    const float* sf = feat_s + (size_t)b * NSHOTB * 128;
    float acc = 0.f;
    int cnt = 0;
    #pragma unroll 4
    for (int s = 0; s < NSHOTB; ++s) {
        float x = sf[s*128 + f];
        bool m = (labL[s] == w);
        acc += m ? x : 0.f;
        cnt += m ? 1 : 0;
    }
    protos[(size_t)blockIdx.x * 128 + f] = acc / (float)cnt;
}

__global__ __launch_bounds__(256) void dist_kernel(
    const float* __restrict__ feat_q, const float* __restrict__ protos,
    float* __restrict__ out)
{
    int idx = blockIdx.x * 256 + threadIdx.x;
    if (idx >= 32 * NQB * NWAY) return;
    int b = idx / (NQB * NWAY);
    int r = idx - b * (NQB * NWAY);
    int q = r / NWAY;
    int w = r - q * NWAY;
    const float* qf = feat_q + (size_t)(b * NQB + q) * 128;
    const float* pp = protos + (size_t)(b * NWAY + w) * 128;
    float d2 = 0.f;
    #pragma unroll 4
    for (int i = 0; i < 128; ++i) { float d = qf[i] - pp[i]; d2 += d * d; }
    out[idx] = -sqrtf(fmaxf(d2, 0.f));
}

// ---------------------------------------------------------------------------
extern "C" void kernel_launch(void* const* d_in, const int* in_sizes, int n_in,
                              void* d_out, int out_size, void* d_ws, size_t ws_size,
                              hipStream_t stream) {
    const float* s_img = (const float*)d_in[0];
    const float* q_img = (const float*)d_in[1];
    const int*   s_lab = (const int*)d_in[2];
    const float* pw1  = (const float*)d_in[3];
    const float* pb1  = (const float*)d_in[4];
    const float* pg1  = (const float*)d_in[5];
    const float* pbe1 = (const float*)d_in[6];
    const float* pm1  = (const float*)d_in[7];
    const float* pv1  = (const float*)d_in[8];
    const float* pw2  = (const float*)d_in[9];
    const float* pb2  = (const float*)d_in[10];
    const float* pg2  = (const float*)d_in[11];
    const float* pbe2 = (const float*)d_in[12];
    const float* pm2  = (const float*)d_in[13];
    const float* pv2  = (const float*)d_in[14];
    const float* pw3  = (const float*)d_in[15];
    const float* pb3  = (const float*)d_in[16];
    const float* pg3  = (const float*)d_in[17];
    const float* pbe3 = (const float*)d_in[18];
    const float* pm3  = (const float*)d_in[19];
    const float* pv3  = (const float*)d_in[20];
    const float* pwf  = (const float*)d_in[21];
    const float* pbf  = (const float*)d_in[22];
    const float* pgf  = (const float*)d_in[23];
    const float* pbef = (const float*)d_in[24];
    const float* pmf  = (const float*)d_in[25];
    const float* pvf  = (const float*)d_in[26];

    const size_t feat_elems = (size_t)NSAMP * 128;      // fp32
    const size_t prot_elems = (size_t)32 * NWAY * 128;  // fp32
    float* feat   = (float*)d_ws;
    float* protos = feat + feat_elems;
    unsigned short* Wf1 = (unsigned short*)(protos + prot_elems);
    unsigned short* Wf2 = Wf1 + 2048;    // 4  frags x 512
    unsigned short* Wf3 = Wf2 + 12288;   // 24 frags x 512; W3 = 96 x 512
    float* out = (float*)d_out;

    prep_weights<<<124, 256, 0, stream>>>(pw1, pw2, pw3, Wf1, Wf2, Wf3);

    encoder_fused<<<NSAMP, 256, 0, stream>>>(
        s_img, q_img,
        Wf1, pb1, pg1, pbe1, pm1, pv1,
        pb2, pg2, pbe2, pm2, pv2, Wf2,
        pb3, pg3, pbe3, pm3, pv3, Wf3,
        pwf, pbf, pgf, pbef, pmf, pvf,
        feat);

    proto_kernel<<<32 * NWAY, 128, 0, stream>>>(feat, s_lab, protos);

    dist_kernel<<<(32 * NQB * NWAY + 255) / 256, 256, 0, stream>>>(
        feat + (size_t)NSUP * 128, protos, out);
}

// Round 2
// 478.734 us; speedup vs baseline: 1.2615x; 1.2615x over previous
//
#include <hip/hip_runtime.h>
#include <math.h>

#define EPS_BN 1e-5f

// Problem constants: B=32, NS=200, NQ=100, C=8, L=512, H=32, F=128, N_WAY=20
#define NSUP   6400
#define NQRY   3200
#define NSAMP  9600
#define NWAY   20
#define NSHOTB 200
#define NQB    100

using short8  = __attribute__((ext_vector_type(8))) short;
using floatx4 = __attribute__((ext_vector_type(4))) float;

// accurate split (prep only): RNE both halves
__device__ __forceinline__ void bf16_split_rn(float x, unsigned& uh, unsigned& ul) {
    unsigned u = __float_as_uint(x);
    uh = (u + 0x7FFFu + ((u >> 16) & 1u)) >> 16;
    float e = x - __uint_as_float(uh << 16);
    unsigned ue = __float_as_uint(e);
    ul = (ue + 0x7FFFu + ((ue >> 16) & 1u)) >> 16;
}
// fast split (hot path): RNE hi, truncated lo
__device__ __forceinline__ void bf16_split_fast(float x, unsigned& uh, unsigned& ul) {
    unsigned u = __float_as_uint(x);
    uh = (u + 0x7FFFu + ((u >> 16) & 1u)) >> 16;
    float e = x - __uint_as_float(uh << 16);
    ul = __float_as_uint(e) >> 16;
}

// ===========================================================================
// prep: W1 [32][8][3], W2 [64][32][3], W3 [128][64][3] -> MFMA B-fragment
// order, split hi/lo bf16 (layouts verified rounds 4-8).
//  W1: frag=nt*2+hl; co=nt*16+(lane&15), k=quad*8+j -> t=quad, ci=j; t==3 -> 0
// ===========================================================================
__global__ __launch_bounds__(256) void prep_weights(
    const float* __restrict__ w1, const float* __restrict__ w2,
    const float* __restrict__ w3, unsigned short* __restrict__ Wf1,
    unsigned short* __restrict__ Wf2, unsigned short* __restrict__ Wf3)
{
    int b = blockIdx.x;
    if (b < 24) {                         // W2: 24 frags x 512
        int e = b * 512 + threadIdx.x;
        #pragma unroll
        for (int r = 0; r < 2; ++r, e += 256) {
            int frag = e >> 9, off = e & 511;
            int lane = off >> 3, j = off & 7;
            int hl = frag & 1, f2 = frag >> 1;
            int nt = f2 & 3, t = f2 >> 2;
            int co = nt * 16 + (lane & 15);
            int ci = (lane >> 4) * 8 + j;
            float x = w2[(co * 32 + ci) * 3 + t];
            unsigned uh, ul; bf16_split_rn(x, uh, ul);
            Wf2[e] = (unsigned short)(hl ? ul : uh);
        }
    } else if (b < 120) {                 // W3: 96 frags x 512
        int e = (b - 24) * 512 + threadIdx.x;
        #pragma unroll
        for (int r = 0; r < 2; ++r, e += 256) {
            int frag = e >> 9, off = e & 511;
            int lane = off >> 3, j = off & 7;
            int hl = frag & 1, f2 = frag >> 1;
            int nt = f2 & 7, f3 = f2 >> 3;
            int ks = f3 & 1, t = f3 >> 1;
            int co = nt * 16 + (lane & 15);
            int ci = ks * 32 + (lane >> 4) * 8 + j;
            float x = w3[(co * 64 + ci) * 3 + t];
            unsigned uh, ul; bf16_split_rn(x, uh, ul);
            Wf3[e] = (unsigned short)(hl ? ul : uh);
        }
    } else {                              // W1: 4 frags x 512
        int e = (b - 120) * 512 + threadIdx.x;
        #pragma unroll
        for (int r = 0; r < 2; ++r, e += 256) {
            int frag = e >> 9, off = e & 511;
            int lane = off >> 3, j = off & 7;
            int hl = frag & 1, nt = frag >> 1;
            int co = nt * 16 + (lane & 15);
            int t  = lane >> 4;           // quad = tap (K = t*8+ci)
            float x = (t < 3) ? w1[(co * 8 + j) * 3 + t] : 0.f;
            unsigned uh, ul; bf16_split_rn(x, uh, ul);
            Wf1[e] = (unsigned short)(hl ? ul : uh);
        }
    }
}

// ===========================================================================
// Fused encoder, all-MFMA convs. Round-0 structure (3 blocks/CU, no spills;
// the 4-blocks/CU experiment spilled ~16 dwords/thread -> reverted), plus:
//  - conv1 3-term (Al*Wl dropped, validated round 1)
//  - conv1 half-1 inputs prefetched into registers under half-0 MFMA
//  - conv2 tap-0 / conv3 (t0,ks0) W-fragments issued BEFORE the phase
//    barrier (latency overlaps barrier drain)
//  - s_setprio(1) around pure-MFMA clusters (independent blocks per SIMD
//    -> scheduler has role diversity to arbitrate)
//  - tail: register feature + shuffle L2-norm
// ===========================================================================
__global__ __launch_bounds__(256, 3) void encoder_fused(
    const float* __restrict__ s_img, const float* __restrict__ q_img,
    const unsigned short* __restrict__ Wf1,
    const float* __restrict__ pb1, const float* __restrict__ pg1,
    const float* __restrict__ pbe1, const float* __restrict__ pm1,
    const float* __restrict__ pv1,
    const float* __restrict__ pb2, const float* __restrict__ pg2,
    const float* __restrict__ pbe2, const float* __restrict__ pm2,
    const float* __restrict__ pv2, const unsigned short* __restrict__ Wf2,
    const float* __restrict__ pb3, const float* __restrict__ pg3,
    const float* __restrict__ pbe3, const float* __restrict__ pm3,
    const float* __restrict__ pv3, const unsigned short* __restrict__ Wf3,
    const float* __restrict__ pwf, const float* __restrict__ pbf,
    const float* __restrict__ pgf, const float* __restrict__ pbef,
    const float* __restrict__ pmf, const float* __restrict__ pvf,
    float* __restrict__ feat_out)
{
    // U regions (time-multiplexed):
    //  conv1/conv2: B1h @0 (20640), B1l @20640 (20640),
    //               Xth @41280 (260 rows x 8 shorts = 4160), Xtl @45440 (4160)
    //  conv3:       X2h @0 (18720), X2l @18720 (18720)
    //  tail:        part @41280 (1024), featm @42304 (512)
    __shared__ __align__(16) char U[49600];
    short* const B1h = (short*)U;
    short* const B1l = (short*)(U + 20640);
    short* const Xth = (short*)(U + 41280);
    short* const Xtl = (short*)(U + 45440);
    short* const X2h = (short*)U;
    short* const X2l = (short*)(U + 18720);
    float* const part  = (float*)(U + 41280);   // [2][128]
    float* const featm = (float*)(U + 42304);   // [128]
    __shared__ float sc1[32], sh1[32], sc2[64], sh2[64], sc3[128], sh3[128];

    const int tid  = threadIdx.x;
    const int sid  = blockIdx.x;
    const int lane = tid & 63;
    const int wid  = tid >> 6;
    const int mrow = lane & 15;
    const int quad = lane >> 4;
    const int kq   = quad * 8;

    const float* xin = (sid < NSUP) ? (s_img + (size_t)sid * 4096)
                                    : (q_img + (size_t)(sid - NSUP) * 4096);

    // ---- init: fold BN params, zero Xt tail rows + B1 halo rows ----
    if (tid < 32) {
        float s = pg1[tid] * rsqrtf(pv1[tid] + EPS_BN);
        sc1[tid] = s; sh1[tid] = (pb1[tid] - pm1[tid]) * s + pbe1[tid];
    } else if (tid < 96) {
        int c = tid - 32;
        float s = pg2[c] * rsqrtf(pv2[c] + EPS_BN);
        sc2[c] = s; sh2[c] = (pb2[c] - pm2[c]) * s + pbe2[c];
    } else if (tid < 224) {
        int c = tid - 96;
        float s = pg3[c] * rsqrtf(pv3[c] + EPS_BN);
        sc3[c] = s; sh3[c] = (pb3[c] - pm3[c]) * s + pbe3[c];
    }
    if (tid < 8) {   // Xt rows 258,259 (quad-3 overreach): zero, avoid NaN bits
        ((unsigned*)(Xth + 258*8))[tid] = 0;
        ((unsigned*)(Xtl + 258*8))[tid] = 0;
    }
    if (tid < 40) {  // B1 halo rows 0, 257 (epilogues never write them)
        B1h[tid] = 0; B1l[tid] = 0;
        B1h[257*40 + tid] = 0; B1l[257*40 + tid] = 0;
    }
    // preload conv1 W fragments (persist in VGPRs)
    short8 W1h[2], W1l[2];
    #pragma unroll
    for (int nt = 0; nt < 2; ++nt) {
        W1h[nt] = *(const short8*)(Wf1 + ((nt*2 + 0)*512 + lane*8));
        W1l[nt] = *(const short8*)(Wf1 + ((nt*2 + 1)*512 + lane*8));
    }

    // hoisted conv2 tap-0 W fragments (loaded before conv1's final barrier)
    short8 W2h0[4], W2l0[4];

    // ---- conv1: 2 halves of 256 pre-pool rows; register input prefetch ----
    float xr[8];
    {
        const int l0 = tid - 1;           // h=0, row tid; l in [-1, 254]
        #pragma unroll
        for (int ci = 0; ci < 8; ++ci)
            xr[ci] = (l0 >= 0) ? xin[ci*512 + l0] : 0.f;
    }
    #pragma unroll
    for (int h = 0; h < 2; ++h) {
        // build Xt row tid from prefetched xr
        {
            short8 vh, vl;
            #pragma unroll
            for (int ci = 0; ci < 8; ++ci) {
                unsigned uh, ul; bf16_split_fast(xr[ci], uh, ul);
                vh[ci] = (short)uh; vl[ci] = (short)ul;
            }
            *(short8*)&Xth[tid*8] = vh;
            *(short8*)&Xtl[tid*8] = vl;
        }
        if (tid < 2) {                    // rows 256, 257
            const int row = 256 + tid;
            const int l = h*256 + row - 1;    // 255/256 (h=0), 511/512 (h=1)
            short8 vh, vl;
            #pragma unroll
            for (int ci = 0; ci < 8; ++ci) {
                float x = (l < 512) ? xin[ci*512 + l] : 0.f;
                unsigned uh, ul; bf16_split_fast(x, uh, ul);
                vh[ci] = (short)uh; vl[ci] = (short)ul;
            }
            *(short8*)&Xth[row*8] = vh;
            *(short8*)&Xtl[row*8] = vl;
        }
        __syncthreads();
        if (h == 0) {                     // prefetch half-1 inputs (l in [255,510])
            const int l = 256 + tid - 1;
            #pragma unroll
            for (int ci = 0; ci < 8; ++ci)
                xr[ci] = xin[ci*512 + l];
        }
        // MFMA sweep: wave owns mt_local {4w..4w+3}; A-frag = one b128/row
        #pragma unroll
        for (int mi = 0; mi < 4; ++mi) {
            const int mtl = wid*4 + mi;
            const int mt  = h*16 + mtl;
            const int row = mtl*16 + mrow + quad;
            const short8 Ah = *(const short8*)&Xth[row*8];
            const short8 Al = *(const short8*)&Xtl[row*8];
            floatx4 a1[2] = {};
            __builtin_amdgcn_s_setprio(1);
            #pragma unroll
            for (int nt = 0; nt < 2; ++nt) {
                a1[nt] = __builtin_amdgcn_mfma_f32_16x16x32_bf16(Ah, W1h[nt], a1[nt], 0, 0, 0);
                a1[nt] = __builtin_amdgcn_mfma_f32_16x16x32_bf16(Ah, W1l[nt], a1[nt], 0, 0, 0);
                a1[nt] = __builtin_amdgcn_mfma_f32_16x16x32_bf16(Al, W1h[nt], a1[nt], 0, 0, 0);
            }
            __builtin_amdgcn_s_setprio(0);
            // epilogue: BN+ReLU+pool2 -> B1 rows
            const int pl0 = mt*8 + quad*2 + 1;   // +1 halo
            #pragma unroll
            for (int nt = 0; nt < 2; ++nt) {
                const int co = nt*16 + mrow;
                const float sc = sc1[co], sh = sh1[co];
                floatx4 d = a1[nt];
                float v0 = fmaxf(0.f, fmaxf(d[0]*sc + sh, d[1]*sc + sh));
                float v1 = fmaxf(0.f, fmaxf(d[2]*sc + sh, d[3]*sc + sh));
                unsigned uh, ul;
                bf16_split_fast(v0, uh, ul);
                B1h[pl0*40 + co] = (short)uh; B1l[pl0*40 + co] = (short)ul;
                bf16_split_fast(v1, uh, ul);
                B1h[(pl0+1)*40 + co] = (short)uh; B1l[(pl0+1)*40 + co] = (short)ul;
            }
        }
        if (h == 1) {   // issue conv2 tap-0 W loads before the barrier
            #pragma unroll
            for (int n = 0; n < 4; ++n) {
                W2h0[n] = *(const short8*)(Wf2 + ((n*2 + 0)*512 + lane*8));
                W2l0[n] = *(const short8*)(Wf2 + ((n*2 + 1)*512 + lane*8));
            }
        }
        __syncthreads();   // protect Xt for next half / B1 complete for conv2
    }

    // ---- conv2 MFMA: M=256, N=64, K=32, 3 taps, 3-term.
    // Wave w owns mt {4w..4w+3} x ALL nt {0..3}.
    floatx4 acc2[4][4] = {};
    #pragma unroll
    for (int t = 0; t < 3; ++t) {
        short8 W2h[4], W2l[4];
        if (t == 0) {
            #pragma unroll
            for (int nt = 0; nt < 4; ++nt) { W2h[nt] = W2h0[nt]; W2l[nt] = W2l0[nt]; }
        } else {
            #pragma unroll
            for (int nt = 0; nt < 4; ++nt) {
                W2h[nt] = *(const short8*)(Wf2 + (((t*4 + nt)*2 + 0)*512 + lane*8));
                W2l[nt] = *(const short8*)(Wf2 + (((t*4 + nt)*2 + 1)*512 + lane*8));
            }
        }
        #pragma unroll
        for (int mi = 0; mi < 4; ++mi) {
            const int mt = wid*4 + mi;
            const int base = (mt*16 + mrow + t)*40 + kq;
            const short8 Ah = *(const short8*)&B1h[base];
            const short8 Al = *(const short8*)&B1l[base];
            __builtin_amdgcn_s_setprio(1);
            #pragma unroll
            for (int nt = 0; nt < 4; ++nt) {
                acc2[mi][nt] = __builtin_amdgcn_mfma_f32_16x16x32_bf16(Ah, W2h[nt], acc2[mi][nt], 0, 0, 0);
                acc2[mi][nt] = __builtin_amdgcn_mfma_f32_16x16x32_bf16(Ah, W2l[nt], acc2[mi][nt], 0, 0, 0);
                acc2[mi][nt] = __builtin_amdgcn_mfma_f32_16x16x32_bf16(Al, W2h[nt], acc2[mi][nt], 0, 0, 0);
            }
            __builtin_amdgcn_s_setprio(0);
        }
    }
    __syncthreads();   // B1 dead

    const int mt0 = (wid & 1) * 4;
    const int ntb = (wid >> 1) * 4;

    // ---- conv2 epilogue -> X2 (BN+ReLU+pool2, split bf16) ----
    {
        #pragma unroll
        for (int mi = 0; mi < 4; ++mi) {
            const int mt = wid*4 + mi;
            const int r0 = mt*8 + quad*2 + 1;
            #pragma unroll
            for (int nt = 0; nt < 4; ++nt) {
                const int co = nt*16 + mrow;
                const float sc = sc2[co], sh = sh2[co];
                floatx4 d = acc2[mi][nt];
                float v0 = fmaxf(0.f, fmaxf(d[0]*sc + sh, d[1]*sc + sh));
                float v1 = fmaxf(0.f, fmaxf(d[2]*sc + sh, d[3]*sc + sh));
                unsigned uh, ul;
                bf16_split_fast(v0, uh, ul);
                X2h[r0*72 + co] = (short)uh; X2l[r0*72 + co] = (short)ul;
                bf16_split_fast(v1, uh, ul);
                X2h[(r0+1)*72 + co] = (short)uh; X2l[(r0+1)*72 + co] = (short)ul;
            }
        }
        if (tid < 72) {
            X2h[tid] = 0; X2l[tid] = 0;
            X2h[129*72 + tid] = 0; X2l[129*72 + tid] = 0;
        }
    }
    // issue conv3 (t=0,ks=0) W loads before the barrier
    short8 W3h0[4], W3l0[4];
    #pragma unroll
    for (int n = 0; n < 4; ++n) {
        W3h0[n] = *(const short8*)(Wf3 + (((ntb + n)*2 + 0)*512 + lane*8));
        W3l0[n] = *(const short8*)(Wf3 + (((ntb + n)*2 + 1)*512 + lane*8));
    }
    __syncthreads();

    // ---- conv3 MFMA: M=128, N=128, K=64, 3 taps, 3-term.
    // Wave w: mt {(w&1)*4..+3} x nt {(w>>1)*4..+3}.
    floatx4 acc3[4][4] = {};
    #pragma unroll
    for (int t = 0; t < 3; ++t) {
        #pragma unroll
        for (int ks = 0; ks < 2; ++ks) {
            const int fb = (t*2 + ks) * 8;
            short8 W3h[4], W3l[4];
            if (t == 0 && ks == 0) {
                #pragma unroll
                for (int n = 0; n < 4; ++n) { W3h[n] = W3h0[n]; W3l[n] = W3l0[n]; }
            } else {
                #pragma unroll
                for (int n = 0; n < 4; ++n) {
                    W3h[n] = *(const short8*)(Wf3 + (((fb + ntb + n)*2 + 0)*512 + lane*8));
                    W3l[n] = *(const short8*)(Wf3 + (((fb + ntb + n)*2 + 1)*512 + lane*8));
                }
            }
            #pragma unroll
            for (int mi = 0; mi < 4; ++mi) {
                const int base = ((mt0 + mi)*16 + mrow + t)*72 + ks*32 + kq;
                const short8 Ah = *(const short8*)&X2h[base];
                const short8 Al = *(const short8*)&X2l[base];
                __builtin_amdgcn_s_setprio(1);
                #pragma unroll
                for (int n = 0; n < 4; ++n) {
                    acc3[mi][n] = __builtin_amdgcn_mfma_f32_16x16x32_bf16(Ah, W3h[n], acc3[mi][n], 0, 0, 0);
                    acc3[mi][n] = __builtin_amdgcn_mfma_f32_16x16x32_bf16(Ah, W3l[n], acc3[mi][n], 0, 0, 0);
                    acc3[mi][n] = __builtin_amdgcn_mfma_f32_16x16x32_bf16(Al, W3h[n], acc3[mi][n], 0, 0, 0);
                }
                __builtin_amdgcn_s_setprio(0);
            }
        }
    }
    __syncthreads();   // X2 reads done; tail arrays live in Xt region

    // ---- conv3 epilogue: BN+ReLU+pool2+mean, 2-wave partial reduction ----
    float s4[4];
    {
        #pragma unroll
        for (int n = 0; n < 4; ++n) {
            const int co = (ntb + n)*16 + mrow;
            const float sc = sc3[co], sh = sh3[co];
            float s = 0.f;
            #pragma unroll
            for (int mi = 0; mi < 4; ++mi) {
                floatx4 d = acc3[mi][n];
                s += fmaxf(0.f, fmaxf(d[0]*sc + sh, d[1]*sc + sh));
                s += fmaxf(0.f, fmaxf(d[2]*sc + sh, d[3]*sc + sh));
            }
            s4[n] = s;
        }
        #pragma unroll
        for (int n = 0; n < 4; ++n) {
            s4[n] += __shfl_xor(s4[n], 16);
            s4[n] += __shfl_xor(s4[n], 32);
        }
        if (lane < 16) {
            #pragma unroll
            for (int n = 0; n < 4; ++n)
                part[(wid & 1)*128 + (ntb + n)*16 + lane] = s4[n];
        }
    }
    __syncthreads();
    if (tid < 128) featm[tid] = (part[tid] + part[128 + tid]) * (1.0f / 64.0f);
    __syncthreads();

    // ---- linear 128->128 + BN + ReLU (register result) + L2 normalize ----
    float vout = 0.f;
    if (tid < 128) {
        const float* wr = pwf + (size_t)tid * 128;
        float s = 0.f;
        #pragma unroll 4
        for (int i = 0; i < 128; i += 4) {
            float4 w4 = *(const float4*)(wr + i);
            s += w4.x*featm[i] + w4.y*featm[i+1] + w4.z*featm[i+2] + w4.w*featm[i+3];
        }
        s += pbf[tid];
        s = (s - pmf[tid]) * (pgf[tid] * rsqrtf(pvf[tid] + EPS_BN)) + pbef[tid];
        vout = fmaxf(s, 0.f);
        float ss = vout * vout;
        ss += __shfl_xor(ss, 1);
        ss += __shfl_xor(ss, 2);
        ss += __shfl_xor(ss, 4);
        ss += __shfl_xor(ss, 8);
        ss += __shfl_xor(ss, 16);
        ss += __shfl_xor(ss, 32);
        if (lane == 0) part[wid] = ss;   // wid 0,1
    }
    __syncthreads();
    if (tid < 128) {
        float n = fmaxf(sqrtf(part[0] + part[1]), 1e-12f);
        feat_out[(size_t)sid * 128 + tid] = vout / n;
    }
}

// ---------------------------------------------------------------------------
// proto: stage labels in LDS, unconditional coalesced feature loads with
// predicated accumulate (no 200-deep dependent global-load chain).
__global__ __launch_bounds__(128) void proto_kernel(
    const float* __restrict__ feat_s, const int* __restrict__ s_lab,
    float* __restrict__ protos)
{
    __shared__ int labL[NSHOTB];
    const int b = blockIdx.x / NWAY;
    const int w = blockIdx.x % NWAY;
    const int f = threadIdx.x;
    const int* lab = s_lab + b * NSHOTB;
    for (int s = f; s < NSHOTB; s += 128) labL[s] = lab[s];
    __syncthreads();
    const float* sf = feat_s + (size_t)b * NSHOTB * 128;
    float acc = 0.f;
    int cnt = 0;
    #pragma unroll 4
    for (int s = 0; s < NSHOTB; ++s) {
        float x = sf[s*128 + f];
        bool m = (labL[s] == w);
        acc += m ? x : 0.f;
        cnt += m ? 1 : 0;
    }
    protos[(size_t)blockIdx.x * 128 + f] = acc / (float)cnt;
}

__global__ __launch_bounds__(256) void dist_kernel(
    const float* __restrict__ feat_q, const float* __restrict__ protos,
    float* __restrict__ out)
{
    int idx = blockIdx.x * 256 + threadIdx.x;
    if (idx >= 32 * NQB * NWAY) return;
    int b = idx / (NQB * NWAY);
    int r = idx - b * (NQB * NWAY);
    int q = r / NWAY;
    int w = r - q * NWAY;
    const float* qf = feat_q + (size_t)(b * NQB + q) * 128;
    const float* pp = protos + (size_t)(b * NWAY + w) * 128;
    float d2 = 0.f;
    #pragma unroll 4
    for (int i = 0; i < 128; ++i) { float d = qf[i] - pp[i]; d2 += d * d; }
    out[idx] = -sqrtf(fmaxf(d2, 0.f));
}

// ---------------------------------------------------------------------------
extern "C" void kernel_launch(void* const* d_in, const int* in_sizes, int n_in,
                              void* d_out, int out_size, void* d_ws, size_t ws_size,
                              hipStream_t stream) {
    const float* s_img = (const float*)d_in[0];
    const float* q_img = (const float*)d_in[1];
    const int*   s_lab = (const int*)d_in[2];
    const float* pw1  = (const float*)d_in[3];
    const float* pb1  = (const float*)d_in[4];
    const float* pg1  = (const float*)d_in[5];
    const float* pbe1 = (const float*)d_in[6];
    const float* pm1  = (const float*)d_in[7];
    const float* pv1  = (const float*)d_in[8];
    const float* pw2  = (const float*)d_in[9];
    const float* pb2  = (const float*)d_in[10];
    const float* pg2  = (const float*)d_in[11];
    const float* pbe2 = (const float*)d_in[12];
    const float* pm2  = (const float*)d_in[13];
    const float* pv2  = (const float*)d_in[14];
    const float* pw3  = (const float*)d_in[15];
    const float* pb3  = (const float*)d_in[16];
    const float* pg3  = (const float*)d_in[17];
    const float* pbe3 = (const float*)d_in[18];
    const float* pm3  = (const float*)d_in[19];
    const float* pv3  = (const float*)d_in[20];
    const float* pwf  = (const float*)d_in[21];
    const float* pbf  = (const float*)d_in[22];
    const float* pgf  = (const float*)d_in[23];
    const float* pbef = (const float*)d_in[24];
    const float* pmf  = (const float*)d_in[25];
    const float* pvf  = (const float*)d_in[26];

    const size_t feat_elems = (size_t)NSAMP * 128;      // fp32
    const size_t prot_elems = (size_t)32 * NWAY * 128;  // fp32
    float* feat   = (float*)d_ws;
    float* protos = feat + feat_elems;
    unsigned short* Wf1 = (unsigned short*)(protos + prot_elems);
    unsigned short* Wf2 = Wf1 + 2048;    // 4  frags x 512
    unsigned short* Wf3 = Wf2 + 12288;   // 24 frags x 512; W3 = 96 x 512
    float* out = (float*)d_out;

    prep_weights<<<124, 256, 0, stream>>>(pw1, pw2, pw3, Wf1, Wf2, Wf3);

    encoder_fused<<<NSAMP, 256, 0, stream>>>(
        s_img, q_img,
        Wf1, pb1, pg1, pbe1, pm1, pv1,
        pb2, pg2, pbe2, pm2, pv2, Wf2,
        pb3, pg3, pbe3, pm3, pv3, Wf3,
        pwf, pbf, pgf, pbef, pmf, pvf,
        feat);

    proto_kernel<<<32 * NWAY, 128, 0, stream>>>(feat, s_lab, protos);

    dist_kernel<<<(32 * NQB * NWAY + 255) / 256, 256, 0, stream>>>(
        feat + (size_t)NSUP * 128, protos, out);
}

// Round 3
// 474.708 us; speedup vs baseline: 1.2722x; 1.0085x over previous
//
#include <hip/hip_runtime.h>
#include <math.h>

#define EPS_BN 1e-5f

// Problem constants: B=32, NS=200, NQ=100, C=8, L=512, H=32, F=128, N_WAY=20
#define NSUP   6400
#define NQRY   3200
#define NSAMP  9600
#define NWAY   20
#define NSHOTB 200
#define NQB    100

using short8  = __attribute__((ext_vector_type(8))) short;
using floatx4 = __attribute__((ext_vector_type(4))) float;

// accurate split (prep only): RNE both halves
__device__ __forceinline__ void bf16_split_rn(float x, unsigned& uh, unsigned& ul) {
    unsigned u = __float_as_uint(x);
    uh = (u + 0x7FFFu + ((u >> 16) & 1u)) >> 16;
    float e = x - __uint_as_float(uh << 16);
    unsigned ue = __float_as_uint(e);
    ul = (ue + 0x7FFFu + ((ue >> 16) & 1u)) >> 16;
}
// fast split (hot path): RNE hi, truncated lo
__device__ __forceinline__ void bf16_split_fast(float x, unsigned& uh, unsigned& ul) {
    unsigned u = __float_as_uint(x);
    uh = (u + 0x7FFFu + ((u >> 16) & 1u)) >> 16;
    float e = x - __uint_as_float(uh << 16);
    ul = __float_as_uint(e) >> 16;
}

// ===========================================================================
// prep: W1 [32][8][3], W2 [64][32][3], W3 [128][64][3] -> MFMA B-fragment
// order, split hi/lo bf16 (layouts verified rounds 4-8).
//  W1: frag=nt*2+hl; co=nt*16+(lane&15), k=quad*8+j -> t=quad, ci=j; t==3 -> 0
// ===========================================================================
__global__ __launch_bounds__(256) void prep_weights(
    const float* __restrict__ w1, const float* __restrict__ w2,
    const float* __restrict__ w3, unsigned short* __restrict__ Wf1,
    unsigned short* __restrict__ Wf2, unsigned short* __restrict__ Wf3)
{
    int b = blockIdx.x;
    if (b < 24) {                         // W2: 24 frags x 512
        int e = b * 512 + threadIdx.x;
        #pragma unroll
        for (int r = 0; r < 2; ++r, e += 256) {
            int frag = e >> 9, off = e & 511;
            int lane = off >> 3, j = off & 7;
            int hl = frag & 1, f2 = frag >> 1;
            int nt = f2 & 3, t = f2 >> 2;
            int co = nt * 16 + (lane & 15);
            int ci = (lane >> 4) * 8 + j;
            float x = w2[(co * 32 + ci) * 3 + t];
            unsigned uh, ul; bf16_split_rn(x, uh, ul);
            Wf2[e] = (unsigned short)(hl ? ul : uh);
        }
    } else if (b < 120) {                 // W3: 96 frags x 512
        int e = (b - 24) * 512 + threadIdx.x;
        #pragma unroll
        for (int r = 0; r < 2; ++r, e += 256) {
            int frag = e >> 9, off = e & 511;
            int lane = off >> 3, j = off & 7;
            int hl = frag & 1, f2 = frag >> 1;
            int nt = f2 & 7, f3 = f2 >> 3;
            int ks = f3 & 1, t = f3 >> 1;
            int co = nt * 16 + (lane & 15);
            int ci = ks * 32 + (lane >> 4) * 8 + j;
            float x = w3[(co * 64 + ci) * 3 + t];
            unsigned uh, ul; bf16_split_rn(x, uh, ul);
            Wf3[e] = (unsigned short)(hl ? ul : uh);
        }
    } else {                              // W1: 4 frags x 512
        int e = (b - 120) * 512 + threadIdx.x;
        #pragma unroll
        for (int r = 0; r < 2; ++r, e += 256) {
            int frag = e >> 9, off = e & 511;
            int lane = off >> 3, j = off & 7;
            int hl = frag & 1, nt = frag >> 1;
            int co = nt * 16 + (lane & 15);
            int t  = lane >> 4;           // quad = tap (K = t*8+ci)
            float x = (t < 3) ? w1[(co * 8 + j) * 3 + t] : 0.f;
            unsigned uh, ul; bf16_split_rn(x, uh, ul);
            Wf1[e] = (unsigned short)(hl ? ul : uh);
        }
    }
}

// ===========================================================================
// Fused encoder, all-MFMA convs. Round-2 structure (3 blocks/CU, setprio,
// issue-early W hoists, conv1 3-term + input prefetch) PLUS:
//  - PHASE STAGGER: counters showed MfmaUtil (42.8%) == per-block serial
//    MFMA fraction (137us/318us) -> co-resident blocks run in lockstep,
//    zero cross-phase overlap. First-generation blocks (bid<768 = 256 CU
//    x 3 residents) spin (bid%3)*8.3us before starting; slot-refill
//    inherits the offset, so conv1 (VALU-heavy) of one block overlaps
//    conv2/3 (MFMA-heavy) of its CU-neighbors for the whole kernel.
//    One-time cost: <=16.7us ragged tail.
// ===========================================================================
__global__ __launch_bounds__(256, 3) void encoder_fused(
    const float* __restrict__ s_img, const float* __restrict__ q_img,
    const unsigned short* __restrict__ Wf1,
    const float* __restrict__ pb1, const float* __restrict__ pg1,
    const float* __restrict__ pbe1, const float* __restrict__ pm1,
    const float* __restrict__ pv1,
    const float* __restrict__ pb2, const float* __restrict__ pg2,
    const float* __restrict__ pbe2, const float* __restrict__ pm2,
    const float* __restrict__ pv2, const unsigned short* __restrict__ Wf2,
    const float* __restrict__ pb3, const float* __restrict__ pg3,
    const float* __restrict__ pbe3, const float* __restrict__ pm3,
    const float* __restrict__ pv3, const unsigned short* __restrict__ Wf3,
    const float* __restrict__ pwf, const float* __restrict__ pbf,
    const float* __restrict__ pgf, const float* __restrict__ pbef,
    const float* __restrict__ pmf, const float* __restrict__ pvf,
    float* __restrict__ feat_out)
{
    // ---- phase stagger (first generation only) ----
    {
        const unsigned r = blockIdx.x % 3u;
        if (blockIdx.x < 768u && r) {
            const unsigned long long tgt = (unsigned long long)r * 830ull; // 10ns ticks ~ 8.3us
            const unsigned long long t0 = __builtin_amdgcn_s_memrealtime();
            while (__builtin_amdgcn_s_memrealtime() - t0 < tgt)
                __builtin_amdgcn_s_sleep(8);
        }
    }

    // U regions (time-multiplexed):
    //  conv1/conv2: B1h @0 (20640), B1l @20640 (20640),
    //               Xth @41280 (260 rows x 8 shorts = 4160), Xtl @45440 (4160)
    //  conv3:       X2h @0 (18720), X2l @18720 (18720)
    //  tail:        part @41280 (1024), featm @42304 (512)
    __shared__ __align__(16) char U[49600];
    short* const B1h = (short*)U;
    short* const B1l = (short*)(U + 20640);
    short* const Xth = (short*)(U + 41280);
    short* const Xtl = (short*)(U + 45440);
    short* const X2h = (short*)U;
    short* const X2l = (short*)(U + 18720);
    float* const part  = (float*)(U + 41280);   // [2][128]
    float* const featm = (float*)(U + 42304);   // [128]
    __shared__ float sc1[32], sh1[32], sc2[64], sh2[64], sc3[128], sh3[128];

    const int tid  = threadIdx.x;
    const int sid  = blockIdx.x;
    const int lane = tid & 63;
    const int wid  = tid >> 6;
    const int mrow = lane & 15;
    const int quad = lane >> 4;
    const int kq   = quad * 8;

    const float* xin = (sid < NSUP) ? (s_img + (size_t)sid * 4096)
                                    : (q_img + (size_t)(sid - NSUP) * 4096);

    // ---- init: fold BN params, zero Xt tail rows + B1 halo rows ----
    if (tid < 32) {
        float s = pg1[tid] * rsqrtf(pv1[tid] + EPS_BN);
        sc1[tid] = s; sh1[tid] = (pb1[tid] - pm1[tid]) * s + pbe1[tid];
    } else if (tid < 96) {
        int c = tid - 32;
        float s = pg2[c] * rsqrtf(pv2[c] + EPS_BN);
        sc2[c] = s; sh2[c] = (pb2[c] - pm2[c]) * s + pbe2[c];
    } else if (tid < 224) {
        int c = tid - 96;
        float s = pg3[c] * rsqrtf(pv3[c] + EPS_BN);
        sc3[c] = s; sh3[c] = (pb3[c] - pm3[c]) * s + pbe3[c];
    }
    if (tid < 8) {   // Xt rows 258,259 (quad-3 overreach): zero, avoid NaN bits
        ((unsigned*)(Xth + 258*8))[tid] = 0;
        ((unsigned*)(Xtl + 258*8))[tid] = 0;
    }
    if (tid < 40) {  // B1 halo rows 0, 257 (epilogues never write them)
        B1h[tid] = 0; B1l[tid] = 0;
        B1h[257*40 + tid] = 0; B1l[257*40 + tid] = 0;
    }
    // preload conv1 W fragments (persist in VGPRs)
    short8 W1h[2], W1l[2];
    #pragma unroll
    for (int nt = 0; nt < 2; ++nt) {
        W1h[nt] = *(const short8*)(Wf1 + ((nt*2 + 0)*512 + lane*8));
        W1l[nt] = *(const short8*)(Wf1 + ((nt*2 + 1)*512 + lane*8));
    }

    // hoisted conv2 tap-0 W fragments (loaded before conv1's final barrier)
    short8 W2h0[4], W2l0[4];

    // ---- conv1: 2 halves of 256 pre-pool rows; register input prefetch ----
    float xr[8];
    {
        const int l0 = tid - 1;           // h=0, row tid; l in [-1, 254]
        #pragma unroll
        for (int ci = 0; ci < 8; ++ci)
            xr[ci] = (l0 >= 0) ? xin[ci*512 + l0] : 0.f;
    }
    #pragma unroll
    for (int h = 0; h < 2; ++h) {
        // build Xt row tid from prefetched xr
        {
            short8 vh, vl;
            #pragma unroll
            for (int ci = 0; ci < 8; ++ci) {
                unsigned uh, ul; bf16_split_fast(xr[ci], uh, ul);
                vh[ci] = (short)uh; vl[ci] = (short)ul;
            }
            *(short8*)&Xth[tid*8] = vh;
            *(short8*)&Xtl[tid*8] = vl;
        }
        if (tid < 2) {                    // rows 256, 257
            const int row = 256 + tid;
            const int l = h*256 + row - 1;    // 255/256 (h=0), 511/512 (h=1)
            short8 vh, vl;
            #pragma unroll
            for (int ci = 0; ci < 8; ++ci) {
                float x = (l < 512) ? xin[ci*512 + l] : 0.f;
                unsigned uh, ul; bf16_split_fast(x, uh, ul);
                vh[ci] = (short)uh; vl[ci] = (short)ul;
            }
            *(short8*)&Xth[row*8] = vh;
            *(short8*)&Xtl[row*8] = vl;
        }
        __syncthreads();
        if (h == 0) {                     // prefetch half-1 inputs (l in [255,510])
            const int l = 256 + tid - 1;
            #pragma unroll
            for (int ci = 0; ci < 8; ++ci)
                xr[ci] = xin[ci*512 + l];
        }
        // MFMA sweep: wave owns mt_local {4w..4w+3}; A-frag = one b128/row
        #pragma unroll
        for (int mi = 0; mi < 4; ++mi) {
            const int mtl = wid*4 + mi;
            const int mt  = h*16 + mtl;
            const int row = mtl*16 + mrow + quad;
            const short8 Ah = *(const short8*)&Xth[row*8];
            const short8 Al = *(const short8*)&Xtl[row*8];
            floatx4 a1[2] = {};
            __builtin_amdgcn_s_setprio(1);
            #pragma unroll
            for (int nt = 0; nt < 2; ++nt) {
                a1[nt] = __builtin_amdgcn_mfma_f32_16x16x32_bf16(Ah, W1h[nt], a1[nt], 0, 0, 0);
                a1[nt] = __builtin_amdgcn_mfma_f32_16x16x32_bf16(Ah, W1l[nt], a1[nt], 0, 0, 0);
                a1[nt] = __builtin_amdgcn_mfma_f32_16x16x32_bf16(Al, W1h[nt], a1[nt], 0, 0, 0);
            }
            __builtin_amdgcn_s_setprio(0);
            // epilogue: BN+ReLU+pool2 -> B1 rows
            const int pl0 = mt*8 + quad*2 + 1;   // +1 halo
            #pragma unroll
            for (int nt = 0; nt < 2; ++nt) {
                const int co = nt*16 + mrow;
                const float sc = sc1[co], sh = sh1[co];
                floatx4 d = a1[nt];
                float v0 = fmaxf(0.f, fmaxf(d[0]*sc + sh, d[1]*sc + sh));
                float v1 = fmaxf(0.f, fmaxf(d[2]*sc + sh, d[3]*sc + sh));
                unsigned uh, ul;
                bf16_split_fast(v0, uh, ul);
                B1h[pl0*40 + co] = (short)uh; B1l[pl0*40 + co] = (short)ul;
                bf16_split_fast(v1, uh, ul);
                B1h[(pl0+1)*40 + co] = (short)uh; B1l[(pl0+1)*40 + co] = (short)ul;
            }
        }
        if (h == 1) {   // issue conv2 tap-0 W loads before the barrier
            #pragma unroll
            for (int n = 0; n < 4; ++n) {
                W2h0[n] = *(const short8*)(Wf2 + ((n*2 + 0)*512 + lane*8));
                W2l0[n] = *(const short8*)(Wf2 + ((n*2 + 1)*512 + lane*8));
            }
        }
        __syncthreads();   // protect Xt for next half / B1 complete for conv2
    }

    // ---- conv2 MFMA: M=256, N=64, K=32, 3 taps, 3-term.
    // Wave w owns mt {4w..4w+3} x ALL nt {0..3}.
    floatx4 acc2[4][4] = {};
    #pragma unroll
    for (int t = 0; t < 3; ++t) {
        short8 W2h[4], W2l[4];
        if (t == 0) {
            #pragma unroll
            for (int nt = 0; nt < 4; ++nt) { W2h[nt] = W2h0[nt]; W2l[nt] = W2l0[nt]; }
        } else {
            #pragma unroll
            for (int nt = 0; nt < 4; ++nt) {
                W2h[nt] = *(const short8*)(Wf2 + (((t*4 + nt)*2 + 0)*512 + lane*8));
                W2l[nt] = *(const short8*)(Wf2 + (((t*4 + nt)*2 + 1)*512 + lane*8));
            }
        }
        #pragma unroll
        for (int mi = 0; mi < 4; ++mi) {
            const int mt = wid*4 + mi;
            const int base = (mt*16 + mrow + t)*40 + kq;
            const short8 Ah = *(const short8*)&B1h[base];
            const short8 Al = *(const short8*)&B1l[base];
            __builtin_amdgcn_s_setprio(1);
            #pragma unroll
            for (int nt = 0; nt < 4; ++nt) {
                acc2[mi][nt] = __builtin_amdgcn_mfma_f32_16x16x32_bf16(Ah, W2h[nt], acc2[mi][nt], 0, 0, 0);
                acc2[mi][nt] = __builtin_amdgcn_mfma_f32_16x16x32_bf16(Ah, W2l[nt], acc2[mi][nt], 0, 0, 0);
                acc2[mi][nt] = __builtin_amdgcn_mfma_f32_16x16x32_bf16(Al, W2h[nt], acc2[mi][nt], 0, 0, 0);
            }
            __builtin_amdgcn_s_setprio(0);
        }
    }
    __syncthreads();   // B1 dead

    const int mt0 = (wid & 1) * 4;
    const int ntb = (wid >> 1) * 4;

    // ---- conv2 epilogue -> X2 (BN+ReLU+pool2, split bf16) ----
    {
        #pragma unroll
        for (int mi = 0; mi < 4; ++mi) {
            const int mt = wid*4 + mi;
            const int r0 = mt*8 + quad*2 + 1;
            #pragma unroll
            for (int nt = 0; nt < 4; ++nt) {
                const int co = nt*16 + mrow;
                const float sc = sc2[co], sh = sh2[co];
                floatx4 d = acc2[mi][nt];
                float v0 = fmaxf(0.f, fmaxf(d[0]*sc + sh, d[1]*sc + sh));
                float v1 = fmaxf(0.f, fmaxf(d[2]*sc + sh, d[3]*sc + sh));
                unsigned uh, ul;
                bf16_split_fast(v0, uh, ul);
                X2h[r0*72 + co] = (short)uh; X2l[r0*72 + co] = (short)ul;
                bf16_split_fast(v1, uh, ul);
                X2h[(r0+1)*72 + co] = (short)uh; X2l[(r0+1)*72 + co] = (short)ul;
            }
        }
        if (tid < 72) {
            X2h[tid] = 0; X2l[tid] = 0;
            X2h[129*72 + tid] = 0; X2l[129*72 + tid] = 0;
        }
    }
    // issue conv3 (t=0,ks=0) W loads before the barrier
    short8 W3h0[4], W3l0[4];
    #pragma unroll
    for (int n = 0; n < 4; ++n) {
        W3h0[n] = *(const short8*)(Wf3 + (((ntb + n)*2 + 0)*512 + lane*8));
        W3l0[n] = *(const short8*)(Wf3 + (((ntb + n)*2 + 1)*512 + lane*8));
    }
    __syncthreads();

    // ---- conv3 MFMA: M=128, N=128, K=64, 3 taps, 3-term.
    // Wave w: mt {(w&1)*4..+3} x nt {(w>>1)*4..+3}.
    floatx4 acc3[4][4] = {};
    #pragma unroll
    for (int t = 0; t < 3; ++t) {
        #pragma unroll
        for (int ks = 0; ks < 2; ++ks) {
            const int fb = (t*2 + ks) * 8;
            short8 W3h[4], W3l[4];
            if (t == 0 && ks == 0) {
                #pragma unroll
                for (int n = 0; n < 4; ++n) { W3h[n] = W3h0[n]; W3l[n] = W3l0[n]; }
            } else {
                #pragma unroll
                for (int n = 0; n < 4; ++n) {
                    W3h[n] = *(const short8*)(Wf3 + (((fb + ntb + n)*2 + 0)*512 + lane*8));
                    W3l[n] = *(const short8*)(Wf3 + (((fb + ntb + n)*2 + 1)*512 + lane*8));
                }
            }
            #pragma unroll
            for (int mi = 0; mi < 4; ++mi) {
                const int base = ((mt0 + mi)*16 + mrow + t)*72 + ks*32 + kq;
                const short8 Ah = *(const short8*)&X2h[base];
                const short8 Al = *(const short8*)&X2l[base];
                __builtin_amdgcn_s_setprio(1);
                #pragma unroll
                for (int n = 0; n < 4; ++n) {
                    acc3[mi][n] = __builtin_amdgcn_mfma_f32_16x16x32_bf16(Ah, W3h[n], acc3[mi][n], 0, 0, 0);
                    acc3[mi][n] = __builtin_amdgcn_mfma_f32_16x16x32_bf16(Ah, W3l[n], acc3[mi][n], 0, 0, 0);
                    acc3[mi][n] = __builtin_amdgcn_mfma_f32_16x16x32_bf16(Al, W3h[n], acc3[mi][n], 0, 0, 0);
                }
                __builtin_amdgcn_s_setprio(0);
            }
        }
    }
    __syncthreads();   // X2 reads done; tail arrays live in Xt region

    // ---- conv3 epilogue: BN+ReLU+pool2+mean, 2-wave partial reduction ----
    float s4[4];
    {
        #pragma unroll
        for (int n = 0; n < 4; ++n) {
            const int co = (ntb + n)*16 + mrow;
            const float sc = sc3[co], sh = sh3[co];
            float s = 0.f;
            #pragma unroll
            for (int mi = 0; mi < 4; ++mi) {
                floatx4 d = acc3[mi][n];
                s += fmaxf(0.f, fmaxf(d[0]*sc + sh, d[1]*sc + sh));
                s += fmaxf(0.f, fmaxf(d[2]*sc + sh, d[3]*sc + sh));
            }
            s4[n] = s;
        }
        #pragma unroll
        for (int n = 0; n < 4; ++n) {
            s4[n] += __shfl_xor(s4[n], 16);
            s4[n] += __shfl_xor(s4[n], 32);
        }
        if (lane < 16) {
            #pragma unroll
            for (int n = 0; n < 4; ++n)
                part[(wid & 1)*128 + (ntb + n)*16 + lane] = s4[n];
        }
    }
    __syncthreads();
    if (tid < 128) featm[tid] = (part[tid] + part[128 + tid]) * (1.0f / 64.0f);
    __syncthreads();

    // ---- linear 128->128 + BN + ReLU (register result) + L2 normalize ----
    float vout = 0.f;
    if (tid < 128) {
        const float* wr = pwf + (size_t)tid * 128;
        float s = 0.f;
        #pragma unroll 4
        for (int i = 0; i < 128; i += 4) {
            float4 w4 = *(const float4*)(wr + i);
            s += w4.x*featm[i] + w4.y*featm[i+1] + w4.z*featm[i+2] + w4.w*featm[i+3];
        }
        s += pbf[tid];
        s = (s - pmf[tid]) * (pgf[tid] * rsqrtf(pvf[tid] + EPS_BN)) + pbef[tid];
        vout = fmaxf(s, 0.f);
        float ss = vout * vout;
        ss += __shfl_xor(ss, 1);
        ss += __shfl_xor(ss, 2);
        ss += __shfl_xor(ss, 4);
        ss += __shfl_xor(ss, 8);
        ss += __shfl_xor(ss, 16);
        ss += __shfl_xor(ss, 32);
        if (lane == 0) part[wid] = ss;   // wid 0,1
    }
    __syncthreads();
    if (tid < 128) {
        float n = fmaxf(sqrtf(part[0] + part[1]), 1e-12f);
        feat_out[(size_t)sid * 128 + tid] = vout / n;
    }
}

// ---------------------------------------------------------------------------
// proto: stage labels in LDS, unconditional coalesced feature loads with
// predicated accumulate (no 200-deep dependent global-load chain).
__global__ __launch_bounds__(128) void proto_kernel(
    const float* __restrict__ feat_s, const int* __restrict__ s_lab,
    float* __restrict__ protos)
{
    __shared__ int labL[NSHOTB];
    const int b = blockIdx.x / NWAY;
    const int w = blockIdx.x % NWAY;
    const int f = threadIdx.x;
    const int* lab = s_lab + b * NSHOTB;
    for (int s = f; s < NSHOTB; s += 128) labL[s] = lab[s];
    __syncthreads();
    const float* sf = feat_s + (size_t)b * NSHOTB * 128;
    float acc = 0.f;
    int cnt = 0;
    #pragma unroll 4
    for (int s = 0; s < NSHOTB; ++s) {
        float x = sf[s*128 + f];
        bool m = (labL[s] == w);
        acc += m ? x : 0.f;
        cnt += m ? 1 : 0;
    }
    protos[(size_t)blockIdx.x * 128 + f] = acc / (float)cnt;
}

__global__ __launch_bounds__(256) void dist_kernel(
    const float* __restrict__ feat_q, const float* __restrict__ protos,
    float* __restrict__ out)
{
    int idx = blockIdx.x * 256 + threadIdx.x;
    if (idx >= 32 * NQB * NWAY) return;
    int b = idx / (NQB * NWAY);
    int r = idx - b * (NQB * NWAY);
    int q = r / NWAY;
    int w = r - q * NWAY;
    const float* qf = feat_q + (size_t)(b * NQB + q) * 128;
    const float* pp = protos + (size_t)(b * NWAY + w) * 128;
    float d2 = 0.f;
    #pragma unroll 4
    for (int i = 0; i < 128; ++i) { float d = qf[i] - pp[i]; d2 += d * d; }
    out[idx] = -sqrtf(fmaxf(d2, 0.f));
}

// ---------------------------------------------------------------------------
extern "C" void kernel_launch(void* const* d_in, const int* in_sizes, int n_in,
                              void* d_out, int out_size, void* d_ws, size_t ws_size,
                              hipStream_t stream) {
    const float* s_img = (const float*)d_in[0];
    const float* q_img = (const float*)d_in[1];
    const int*   s_lab = (const int*)d_in[2];
    const float* pw1  = (const float*)d_in[3];
    const float* pb1  = (const float*)d_in[4];
    const float* pg1  = (const float*)d_in[5];
    const float* pbe1 = (const float*)d_in[6];
    const float* pm1  = (const float*)d_in[7];
    const float* pv1  = (const float*)d_in[8];
    const float* pw2  = (const float*)d_in[9];
    const float* pb2  = (const float*)d_in[10];
    const float* pg2  = (const float*)d_in[11];
    const float* pbe2 = (const float*)d_in[12];
    const float* pm2  = (const float*)d_in[13];
    const float* pv2  = (const float*)d_in[14];
    const float* pw3  = (const float*)d_in[15];
    const float* pb3  = (const float*)d_in[16];
    const float* pg3  = (const float*)d_in[17];
    const float* pbe3 = (const float*)d_in[18];
    const float* pm3  = (const float*)d_in[19];
    const float* pv3  = (const float*)d_in[20];
    const float* pwf  = (const float*)d_in[21];
    const float* pbf  = (const float*)d_in[22];
    const float* pgf  = (const float*)d_in[23];
    const float* pbef = (const float*)d_in[24];
    const float* pmf  = (const float*)d_in[25];
    const float* pvf  = (const float*)d_in[26];

    const size_t feat_elems = (size_t)NSAMP * 128;      // fp32
    const size_t prot_elems = (size_t)32 * NWAY * 128;  // fp32
    float* feat   = (float*)d_ws;
    float* protos = feat + feat_elems;
    unsigned short* Wf1 = (unsigned short*)(protos + prot_elems);
    unsigned short* Wf2 = Wf1 + 2048;    // 4  frags x 512
    unsigned short* Wf3 = Wf2 + 12288;   // 24 frags x 512; W3 = 96 x 512
    float* out = (float*)d_out;

    prep_weights<<<124, 256, 0, stream>>>(pw1, pw2, pw3, Wf1, Wf2, Wf3);

    encoder_fused<<<NSAMP, 256, 0, stream>>>(
        s_img, q_img,
        Wf1, pb1, pg1, pbe1, pm1, pv1,
        pb2, pg2, pbe2, pm2, pv2, Wf2,
        pb3, pg3, pbe3, pm3, pv3, Wf3,
        pwf, pbf, pgf, pbef, pmf, pvf,
        feat);

    proto_kernel<<<32 * NWAY, 128, 0, stream>>>(feat, s_lab, protos);

    dist_kernel<<<(32 * NQB * NWAY + 255) / 256, 256, 0, stream>>>(
        feat + (size_t)NSUP * 128, protos, out);
}

// Round 4
// 428.974 us; speedup vs baseline: 1.4078x; 1.1066x over previous
//
#include <hip/hip_runtime.h>
#include <hip/hip_fp16.h>
#include <math.h>

#define EPS_BN 1e-5f

// Problem constants: B=32, NS=200, NQ=100, C=8, L=512, H=32, F=128, N_WAY=20
#define NSUP   6400
#define NQRY   3200
#define NSAMP  9600
#define NWAY   20
#define NSHOTB 200
#define NQB    100

using short8  = __attribute__((ext_vector_type(8))) short;
using half8   = __attribute__((ext_vector_type(8))) _Float16;
using floatx4 = __attribute__((ext_vector_type(4))) float;

// fp16 split: hi = RNE(x), lo = RNE(x - hi). Residual x-hi is EXACT in f32
// (Sterbenz), so A-operand 2-term error is ~2^-21.
__device__ __forceinline__ void f16_split(float x, unsigned short& uh, unsigned short& ul) {
    _Float16 hh = (_Float16)x;
    float r = x - (float)hh;
    _Float16 hl = (_Float16)r;
    uh = __builtin_bit_cast(unsigned short, hh);
    ul = __builtin_bit_cast(unsigned short, hl);
}
__device__ __forceinline__ unsigned short f16_rn(float x) {
    _Float16 h = (_Float16)x;
    return __builtin_bit_cast(unsigned short, h);
}

// ===========================================================================
// prep: W1 [32][8][3], W2 [64][32][3], W3 [128][64][3] -> MFMA B-fragment
// order (layouts verified rounds 4-8 of prior session; dtype-independent).
// fp16: W2/W3 SINGLE fragment (rounding 2^-11, compensated by exact A-split);
// W1 hi/lo pair (conv1 stays 3-term: near-exact first layer).
//  W1: frag=nt*2+hl; co=nt*16+(lane&15), k=quad*8+j -> t=quad, ci=j; t==3 -> 0
// ===========================================================================
__global__ __launch_bounds__(256) void prep_weights(
    const float* __restrict__ w1, const float* __restrict__ w2,
    const float* __restrict__ w3, unsigned short* __restrict__ Wf1,
    unsigned short* __restrict__ Wf2, unsigned short* __restrict__ Wf3)
{
    int b = blockIdx.x;
    if (b < 12) {                         // W2: 12 frags x 512 (single fp16)
        int e = b * 512 + threadIdx.x;
        #pragma unroll
        for (int r = 0; r < 2; ++r, e += 256) {
            int frag = e >> 9, off = e & 511;
            int lane = off >> 3, j = off & 7;
            int nt = frag & 3, t = frag >> 2;
            int co = nt * 16 + (lane & 15);
            int ci = (lane >> 4) * 8 + j;
            Wf2[e] = f16_rn(w2[(co * 32 + ci) * 3 + t]);
        }
    } else if (b < 60) {                  // W3: 48 frags x 512 (single fp16)
        int e = (b - 12) * 512 + threadIdx.x;
        #pragma unroll
        for (int r = 0; r < 2; ++r, e += 256) {
            int frag = e >> 9, off = e & 511;
            int lane = off >> 3, j = off & 7;
            int nt = frag & 7, f3 = frag >> 3;
            int ks = f3 & 1, t = f3 >> 1;
            int co = nt * 16 + (lane & 15);
            int ci = ks * 32 + (lane >> 4) * 8 + j;
            Wf3[e] = f16_rn(w3[(co * 64 + ci) * 3 + t]);
        }
    } else {                              // W1: 4 frags x 512 (hi/lo fp16)
        int e = (b - 60) * 512 + threadIdx.x;
        #pragma unroll
        for (int r = 0; r < 2; ++r, e += 256) {
            int frag = e >> 9, off = e & 511;
            int lane = off >> 3, j = off & 7;
            int hl = frag & 1, nt = frag >> 1;
            int co = nt * 16 + (lane & 15);
            int t  = lane >> 4;           // quad = tap (K = t*8+ci)
            float x = (t < 3) ? w1[(co * 8 + j) * 3 + t] : 0.f;
            unsigned short uh, ul; f16_split(x, uh, ul);
            Wf1[e] = hl ? ul : uh;
        }
    }
}

// ===========================================================================
// Fused encoder, all-MFMA convs, fp16 numerics.
// Round-3 post-mortem: MFMA+VALU pipes already ~81% packed vs demand; the
// lever is LESS WORK. fp16 scheme:
//  - A operand: exact 2-term split (hi RNE + exact residual), stored h/l in
//    LDS exactly as the old bf16 pipeline (same layouts, strides, barriers).
//  - W operand: conv2/conv3 single fp16 (2 MFMA/tile, was 3); conv1 keeps
//    3-term hi/lo W (first layer near-exact, only 16 extra MFMA/wave).
//  Per-wave MFMA 480 -> 336. W regs & W fetches halve. Splits cheaper
//  (4 VALU vs ~6). Stagger removed (round-3: refuted, no effect).
//  Kept: 3 blocks/CU, setprio on MFMA clusters, issue-early W hoists,
//  conv1 input register prefetch, register tail + shuffle L2-norm.
// ===========================================================================
__global__ __launch_bounds__(256, 3) void encoder_fused(
    const float* __restrict__ s_img, const float* __restrict__ q_img,
    const unsigned short* __restrict__ Wf1,
    const float* __restrict__ pb1, const float* __restrict__ pg1,
    const float* __restrict__ pbe1, const float* __restrict__ pm1,
    const float* __restrict__ pv1,
    const float* __restrict__ pb2, const float* __restrict__ pg2,
    const float* __restrict__ pbe2, const float* __restrict__ pm2,
    const float* __restrict__ pv2, const unsigned short* __restrict__ Wf2,
    const float* __restrict__ pb3, const float* __restrict__ pg3,
    const float* __restrict__ pbe3, const float* __restrict__ pm3,
    const float* __restrict__ pv3, const unsigned short* __restrict__ Wf3,
    const float* __restrict__ pwf, const float* __restrict__ pbf,
    const float* __restrict__ pgf, const float* __restrict__ pbef,
    const float* __restrict__ pmf, const float* __restrict__ pvf,
    float* __restrict__ feat_out)
{
    // U regions (time-multiplexed):
    //  conv1/conv2: B1h @0 (20640), B1l @20640 (20640),
    //               Xth @41280 (260 rows x 8 shorts = 4160), Xtl @45440 (4160)
    //  conv3:       X2h @0 (18720), X2l @18720 (18720)
    //  tail:        part @41280 (1024), featm @42304 (512)
    __shared__ __align__(16) char U[49600];
    short* const B1h = (short*)U;
    short* const B1l = (short*)(U + 20640);
    short* const Xth = (short*)(U + 41280);
    short* const Xtl = (short*)(U + 45440);
    short* const X2h = (short*)U;
    short* const X2l = (short*)(U + 18720);
    float* const part  = (float*)(U + 41280);   // [2][128]
    float* const featm = (float*)(U + 42304);   // [128]
    __shared__ float sc1[32], sh1[32], sc2[64], sh2[64], sc3[128], sh3[128];

    const int tid  = threadIdx.x;
    const int sid  = blockIdx.x;
    const int lane = tid & 63;
    const int wid  = tid >> 6;
    const int mrow = lane & 15;
    const int quad = lane >> 4;
    const int kq   = quad * 8;

    const float* xin = (sid < NSUP) ? (s_img + (size_t)sid * 4096)
                                    : (q_img + (size_t)(sid - NSUP) * 4096);

    // ---- init: fold BN params, zero Xt tail rows + B1 halo rows ----
    if (tid < 32) {
        float s = pg1[tid] * rsqrtf(pv1[tid] + EPS_BN);
        sc1[tid] = s; sh1[tid] = (pb1[tid] - pm1[tid]) * s + pbe1[tid];
    } else if (tid < 96) {
        int c = tid - 32;
        float s = pg2[c] * rsqrtf(pv2[c] + EPS_BN);
        sc2[c] = s; sh2[c] = (pb2[c] - pm2[c]) * s + pbe2[c];
    } else if (tid < 224) {
        int c = tid - 96;
        float s = pg3[c] * rsqrtf(pv3[c] + EPS_BN);
        sc3[c] = s; sh3[c] = (pb3[c] - pm3[c]) * s + pbe3[c];
    }
    if (tid < 8) {   // Xt rows 258,259 (quad-3 overreach): zero, avoid NaN bits
        ((unsigned*)(Xth + 258*8))[tid] = 0;
        ((unsigned*)(Xtl + 258*8))[tid] = 0;
    }
    if (tid < 40) {  // B1 halo rows 0, 257 (epilogues never write them)
        B1h[tid] = 0; B1l[tid] = 0;
        B1h[257*40 + tid] = 0; B1l[257*40 + tid] = 0;
    }
    // preload conv1 W fragments (persist in VGPRs)
    half8 W1h[2], W1l[2];
    #pragma unroll
    for (int nt = 0; nt < 2; ++nt) {
        W1h[nt] = *(const half8*)(Wf1 + ((nt*2 + 0)*512 + lane*8));
        W1l[nt] = *(const half8*)(Wf1 + ((nt*2 + 1)*512 + lane*8));
    }

    // hoisted conv2 tap-0 W fragments (loaded before conv1's final barrier)
    half8 W2t0[4];

    // ---- conv1: 2 halves of 256 pre-pool rows; register input prefetch ----
    float xr[8];
    {
        const int l0 = tid - 1;           // h=0, row tid; l in [-1, 254]
        #pragma unroll
        for (int ci = 0; ci < 8; ++ci)
            xr[ci] = (l0 >= 0) ? xin[ci*512 + l0] : 0.f;
    }
    #pragma unroll
    for (int h = 0; h < 2; ++h) {
        // build Xt row tid from prefetched xr (fp16 exact 2-term split)
        {
            half8 vh, vl;
            #pragma unroll
            for (int ci = 0; ci < 8; ++ci) {
                _Float16 hh = (_Float16)xr[ci];
                float r = xr[ci] - (float)hh;
                vh[ci] = hh; vl[ci] = (_Float16)r;
            }
            *(half8*)&Xth[tid*8] = vh;
            *(half8*)&Xtl[tid*8] = vl;
        }
        if (tid < 2) {                    // rows 256, 257
            const int row = 256 + tid;
            const int l = h*256 + row - 1;    // 255/256 (h=0), 511/512 (h=1)
            half8 vh, vl;
            #pragma unroll
            for (int ci = 0; ci < 8; ++ci) {
                float x = (l < 512) ? xin[ci*512 + l] : 0.f;
                _Float16 hh = (_Float16)x;
                float r = x - (float)hh;
                vh[ci] = hh; vl[ci] = (_Float16)r;
            }
            *(half8*)&Xth[row*8] = vh;
            *(half8*)&Xtl[row*8] = vl;
        }
        __syncthreads();
        if (h == 0) {                     // prefetch half-1 inputs (l in [255,510])
            const int l = 256 + tid - 1;
            #pragma unroll
            for (int ci = 0; ci < 8; ++ci)
                xr[ci] = xin[ci*512 + l];
        }
        // MFMA sweep: wave owns mt_local {4w..4w+3}; A-frag = one b128/row
        #pragma unroll
        for (int mi = 0; mi < 4; ++mi) {
            const int mtl = wid*4 + mi;
            const int mt  = h*16 + mtl;
            const int row = mtl*16 + mrow + quad;
            const half8 Ah = *(const half8*)&Xth[row*8];
            const half8 Al = *(const half8*)&Xtl[row*8];
            floatx4 a1[2] = {};
            __builtin_amdgcn_s_setprio(1);
            #pragma unroll
            for (int nt = 0; nt < 2; ++nt) {
                a1[nt] = __builtin_amdgcn_mfma_f32_16x16x32_f16(Ah, W1h[nt], a1[nt], 0, 0, 0);
                a1[nt] = __builtin_amdgcn_mfma_f32_16x16x32_f16(Ah, W1l[nt], a1[nt], 0, 0, 0);
                a1[nt] = __builtin_amdgcn_mfma_f32_16x16x32_f16(Al, W1h[nt], a1[nt], 0, 0, 0);
            }
            __builtin_amdgcn_s_setprio(0);
            // epilogue: BN+ReLU+pool2 -> B1 rows (fp16 h/l)
            const int pl0 = mt*8 + quad*2 + 1;   // +1 halo
            #pragma unroll
            for (int nt = 0; nt < 2; ++nt) {
                const int co = nt*16 + mrow;
                const float sc = sc1[co], sh = sh1[co];
                floatx4 d = a1[nt];
                float v0 = fmaxf(0.f, fmaxf(d[0]*sc + sh, d[1]*sc + sh));
                float v1 = fmaxf(0.f, fmaxf(d[2]*sc + sh, d[3]*sc + sh));
                unsigned short uh, ul;
                f16_split(v0, uh, ul);
                B1h[pl0*40 + co] = (short)uh; B1l[pl0*40 + co] = (short)ul;
                f16_split(v1, uh, ul);
                B1h[(pl0+1)*40 + co] = (short)uh; B1l[(pl0+1)*40 + co] = (short)ul;
            }
        }
        if (h == 1) {   // issue conv2 tap-0 W loads before the barrier
            #pragma unroll
            for (int n = 0; n < 4; ++n)
                W2t0[n] = *(const half8*)(Wf2 + (n*512 + lane*8));
        }
        __syncthreads();   // protect Xt for next half / B1 complete for conv2
    }

    // ---- conv2 MFMA: M=256, N=64, K=32, 3 taps, 2-term (Ah+Al)*W.
    // Wave w owns mt {4w..4w+3} x ALL nt {0..3}.
    floatx4 acc2[4][4] = {};
    #pragma unroll
    for (int t = 0; t < 3; ++t) {
        half8 W2[4];
        if (t == 0) {
            #pragma unroll
            for (int nt = 0; nt < 4; ++nt) W2[nt] = W2t0[nt];
        } else {
            #pragma unroll
            for (int nt = 0; nt < 4; ++nt)
                W2[nt] = *(const half8*)(Wf2 + ((t*4 + nt)*512 + lane*8));
        }
        #pragma unroll
        for (int mi = 0; mi < 4; ++mi) {
            const int mt = wid*4 + mi;
            const int base = (mt*16 + mrow + t)*40 + kq;
            const half8 Ah = *(const half8*)&B1h[base];
            const half8 Al = *(const half8*)&B1l[base];
            __builtin_amdgcn_s_setprio(1);
            #pragma unroll
            for (int nt = 0; nt < 4; ++nt) {
                acc2[mi][nt] = __builtin_amdgcn_mfma_f32_16x16x32_f16(Ah, W2[nt], acc2[mi][nt], 0, 0, 0);
                acc2[mi][nt] = __builtin_amdgcn_mfma_f32_16x16x32_f16(Al, W2[nt], acc2[mi][nt], 0, 0, 0);
            }
            __builtin_amdgcn_s_setprio(0);
        }
    }
    __syncthreads();   // B1 dead

    const int mt0 = (wid & 1) * 4;
    const int ntb = (wid >> 1) * 4;

    // ---- conv2 epilogue -> X2 (BN+ReLU+pool2, fp16 h/l) ----
    {
        #pragma unroll
        for (int mi = 0; mi < 4; ++mi) {
            const int mt = wid*4 + mi;
            const int r0 = mt*8 + quad*2 + 1;
            #pragma unroll
            for (int nt = 0; nt < 4; ++nt) {
                const int co = nt*16 + mrow;
                const float sc = sc2[co], sh = sh2[co];
                floatx4 d = acc2[mi][nt];
                float v0 = fmaxf(0.f, fmaxf(d[0]*sc + sh, d[1]*sc + sh));
                float v1 = fmaxf(0.f, fmaxf(d[2]*sc + sh, d[3]*sc + sh));
                unsigned short uh, ul;
                f16_split(v0, uh, ul);
                X2h[r0*72 + co] = (short)uh; X2l[r0*72 + co] = (short)ul;
                f16_split(v1, uh, ul);
                X2h[(r0+1)*72 + co] = (short)uh; X2l[(r0+1)*72 + co] = (short)ul;
            }
        }
        if (tid < 72) {
            X2h[tid] = 0; X2l[tid] = 0;
            X2h[129*72 + tid] = 0; X2l[129*72 + tid] = 0;
        }
    }
    // issue conv3 (t=0,ks=0) W loads before the barrier
    half8 W3t0[4];
    #pragma unroll
    for (int n = 0; n < 4; ++n)
        W3t0[n] = *(const half8*)(Wf3 + ((ntb + n)*512 + lane*8));
    __syncthreads();

    // ---- conv3 MFMA: M=128, N=128, K=64, 3 taps, 2-term.
    // Wave w: mt {(w&1)*4..+3} x nt {(w>>1)*4..+3}.
    floatx4 acc3[4][4] = {};
    #pragma unroll
    for (int t = 0; t < 3; ++t) {
        #pragma unroll
        for (int ks = 0; ks < 2; ++ks) {
            const int fb = (t*2 + ks) * 8;
            half8 W3[4];
            if (t == 0 && ks == 0) {
                #pragma unroll
                for (int n = 0; n < 4; ++n) W3[n] = W3t0[n];
            } else {
                #pragma unroll
                for (int n = 0; n < 4; ++n)
                    W3[n] = *(const half8*)(Wf3 + ((fb + ntb + n)*512 + lane*8));
            }
            #pragma unroll
            for (int mi = 0; mi < 4; ++mi) {
                const int base = ((mt0 + mi)*16 + mrow + t)*72 + ks*32 + kq;
                const half8 Ah = *(const half8*)&X2h[base];
                const half8 Al = *(const half8*)&X2l[base];
                __builtin_amdgcn_s_setprio(1);
                #pragma unroll
                for (int n = 0; n < 4; ++n) {
                    acc3[mi][n] = __builtin_amdgcn_mfma_f32_16x16x32_f16(Ah, W3[n], acc3[mi][n], 0, 0, 0);
                    acc3[mi][n] = __builtin_amdgcn_mfma_f32_16x16x32_f16(Al, W3[n], acc3[mi][n], 0, 0, 0);
                }
                __builtin_amdgcn_s_setprio(0);
            }
        }
    }
    __syncthreads();   // X2 reads done; tail arrays live in Xt region

    // ---- conv3 epilogue: BN+ReLU+pool2+mean, 2-wave partial reduction ----
    float s4[4];
    {
        #pragma unroll
        for (int n = 0; n < 4; ++n) {
            const int co = (ntb + n)*16 + mrow;
            const float sc = sc3[co], sh = sh3[co];
            float s = 0.f;
            #pragma unroll
            for (int mi = 0; mi < 4; ++mi) {
                floatx4 d = acc3[mi][n];
                s += fmaxf(0.f, fmaxf(d[0]*sc + sh, d[1]*sc + sh));
                s += fmaxf(0.f, fmaxf(d[2]*sc + sh, d[3]*sc + sh));
            }
            s4[n] = s;
        }
        #pragma unroll
        for (int n = 0; n < 4; ++n) {
            s4[n] += __shfl_xor(s4[n], 16);
            s4[n] += __shfl_xor(s4[n], 32);
        }
        if (lane < 16) {
            #pragma unroll
            for (int n = 0; n < 4; ++n)
                part[(wid & 1)*128 + (ntb + n)*16 + lane] = s4[n];
        }
    }
    __syncthreads();
    if (tid < 128) featm[tid] = (part[tid] + part[128 + tid]) * (1.0f / 64.0f);
    __syncthreads();

    // ---- linear 128->128 + BN + ReLU (register result) + L2 normalize ----
    float vout = 0.f;
    if (tid < 128) {
        const float* wr = pwf + (size_t)tid * 128;
        float s = 0.f;
        #pragma unroll 4
        for (int i = 0; i < 128; i += 4) {
            float4 w4 = *(const float4*)(wr + i);
            s += w4.x*featm[i] + w4.y*featm[i+1] + w4.z*featm[i+2] + w4.w*featm[i+3];
        }
        s += pbf[tid];
        s = (s - pmf[tid]) * (pgf[tid] * rsqrtf(pvf[tid] + EPS_BN)) + pbef[tid];
        vout = fmaxf(s, 0.f);
        float ss = vout * vout;
        ss += __shfl_xor(ss, 1);
        ss += __shfl_xor(ss, 2);
        ss += __shfl_xor(ss, 4);
        ss += __shfl_xor(ss, 8);
        ss += __shfl_xor(ss, 16);
        ss += __shfl_xor(ss, 32);
        if (lane == 0) part[wid] = ss;   // wid 0,1
    }
    __syncthreads();
    if (tid < 128) {
        float n = fmaxf(sqrtf(part[0] + part[1]), 1e-12f);
        feat_out[(size_t)sid * 128 + tid] = vout / n;
    }
}

// ---------------------------------------------------------------------------
// proto: stage labels in LDS, unconditional coalesced feature loads with
// predicated accumulate (no 200-deep dependent global-load chain).
__global__ __launch_bounds__(128) void proto_kernel(
    const float* __restrict__ feat_s, const int* __restrict__ s_lab,
    float* __restrict__ protos)
{
    __shared__ int labL[NSHOTB];
    const int b = blockIdx.x / NWAY;
    const int w = blockIdx.x % NWAY;
    const int f = threadIdx.x;
    const int* lab = s_lab + b * NSHOTB;
    for (int s = f; s < NSHOTB; s += 128) labL[s] = lab[s];
    __syncthreads();
    const float* sf = feat_s + (size_t)b * NSHOTB * 128;
    float acc = 0.f;
    int cnt = 0;
    #pragma unroll 4
    for (int s = 0; s < NSHOTB; ++s) {
        float x = sf[s*128 + f];
        bool m = (labL[s] == w);
        acc += m ? x : 0.f;
        cnt += m ? 1 : 0;
    }
    protos[(size_t)blockIdx.x * 128 + f] = acc / (float)cnt;
}

__global__ __launch_bounds__(256) void dist_kernel(
    const float* __restrict__ feat_q, const float* __restrict__ protos,
    float* __restrict__ out)
{
    int idx = blockIdx.x * 256 + threadIdx.x;
    if (idx >= 32 * NQB * NWAY) return;
    int b = idx / (NQB * NWAY);
    int r = idx - b * (NQB * NWAY);
    int q = r / NWAY;
    int w = r - q * NWAY;
    const float* qf = feat_q + (size_t)(b * NQB + q) * 128;
    const float* pp = protos + (size_t)(b * NWAY + w) * 128;
    float d2 = 0.f;
    #pragma unroll 4
    for (int i = 0; i < 128; ++i) { float d = qf[i] - pp[i]; d2 += d * d; }
    out[idx] = -sqrtf(fmaxf(d2, 0.f));
}

// ---------------------------------------------------------------------------
extern "C" void kernel_launch(void* const* d_in, const int* in_sizes, int n_in,
                              void* d_out, int out_size, void* d_ws, size_t ws_size,
                              hipStream_t stream) {
    const float* s_img = (const float*)d_in[0];
    const float* q_img = (const float*)d_in[1];
    const int*   s_lab = (const int*)d_in[2];
    const float* pw1  = (const float*)d_in[3];
    const float* pb1  = (const float*)d_in[4];
    const float* pg1  = (const float*)d_in[5];
    const float* pbe1 = (const float*)d_in[6];
    const float* pm1  = (const float*)d_in[7];
    const float* pv1  = (const float*)d_in[8];
    const float* pw2  = (const float*)d_in[9];
    const float* pb2  = (const float*)d_in[10];
    const float* pg2  = (const float*)d_in[11];
    const float* pbe2 = (const float*)d_in[12];
    const float* pm2  = (const float*)d_in[13];
    const float* pv2  = (const float*)d_in[14];
    const float* pw3  = (const float*)d_in[15];
    const float* pb3  = (const float*)d_in[16];
    const float* pg3  = (const float*)d_in[17];
    const float* pbe3 = (const float*)d_in[18];
    const float* pm3  = (const float*)d_in[19];
    const float* pv3  = (const float*)d_in[20];
    const float* pwf  = (const float*)d_in[21];
    const float* pbf  = (const float*)d_in[22];
    const float* pgf  = (const float*)d_in[23];
    const float* pbef = (const float*)d_in[24];
    const float* pmf  = (const float*)d_in[25];
    const float* pvf  = (const float*)d_in[26];

    const size_t feat_elems = (size_t)NSAMP * 128;      // fp32
    const size_t prot_elems = (size_t)32 * NWAY * 128;  // fp32
    float* feat   = (float*)d_ws;
    float* protos = feat + feat_elems;
    unsigned short* Wf1 = (unsigned short*)(protos + prot_elems);
    unsigned short* Wf2 = Wf1 + 2048;    // W1: 4 frags x 512 (h/l)
    unsigned short* Wf3 = Wf2 + 6144;    // W2: 12 frags x 512; W3: 48 x 512
    float* out = (float*)d_out;

    prep_weights<<<64, 256, 0, stream>>>(pw1, pw2, pw3, Wf1, Wf2, Wf3);

    encoder_fused<<<NSAMP, 256, 0, stream>>>(
        s_img, q_img,
        Wf1, pb1, pg1, pbe1, pm1, pv1,
        pb2, pg2, pbe2, pm2, pv2, Wf2,
        pb3, pg3, pbe3, pm3, pv3, Wf3,
        pwf, pbf, pgf, pbef, pmf, pvf,
        feat);

    proto_kernel<<<32 * NWAY, 128, 0, stream>>>(feat, s_lab, protos);

    dist_kernel<<<(32 * NQB * NWAY + 255) / 256, 256, 0, stream>>>(
        feat + (size_t)NSUP * 128, protos, out);
}

// Round 5
// 387.282 us; speedup vs baseline: 1.5594x; 1.1077x over previous
//
#include <hip/hip_runtime.h>
#include <hip/hip_fp16.h>
#include <math.h>

#define EPS_BN 1e-5f

// Problem constants: B=32, NS=200, NQ=100, C=8, L=512, H=32, F=128, N_WAY=20
#define NSUP   6400
#define NQRY   3200
#define NSAMP  9600
#define NWAY   20
#define NSHOTB 200
#define NQB    100

using short8  = __attribute__((ext_vector_type(8))) short;
using half8   = __attribute__((ext_vector_type(8))) _Float16;
using floatx4 = __attribute__((ext_vector_type(4))) float;

// fp16 split: hi = RNE(x), lo = RNE(x - hi). Residual x-hi is EXACT in f32
// (Sterbenz), so 2-term error ~2^-21.
__device__ __forceinline__ void f16_split(float x, unsigned short& uh, unsigned short& ul) {
    _Float16 hh = (_Float16)x;
    float r = x - (float)hh;
    _Float16 hl = (_Float16)r;
    uh = __builtin_bit_cast(unsigned short, hh);
    ul = __builtin_bit_cast(unsigned short, hl);
}
__device__ __forceinline__ unsigned short f16_rn(float x) {
    _Float16 h = (_Float16)x;
    return __builtin_bit_cast(unsigned short, h);
}

// ===========================================================================
// prep: W1 [32][8][3], W2 [64][32][3], W3 [128][64][3] -> MFMA B-fragment
// order (layouts verified earlier; dtype-independent).
// W2/W3 single fp16 fragment; W1 hi/lo pair (conv1 stays 3-term).
//  W1: frag=nt*2+hl; co=nt*16+(lane&15), k=quad*8+j -> t=quad, ci=j; t==3 -> 0
// ===========================================================================
__global__ __launch_bounds__(256) void prep_weights(
    const float* __restrict__ w1, const float* __restrict__ w2,
    const float* __restrict__ w3, unsigned short* __restrict__ Wf1,
    unsigned short* __restrict__ Wf2, unsigned short* __restrict__ Wf3)
{
    int b = blockIdx.x;
    if (b < 12) {                         // W2: 12 frags x 512 (single fp16)
        int e = b * 512 + threadIdx.x;
        #pragma unroll
        for (int r = 0; r < 2; ++r, e += 256) {
            int frag = e >> 9, off = e & 511;
            int lane = off >> 3, j = off & 7;
            int nt = frag & 3, t = frag >> 2;
            int co = nt * 16 + (lane & 15);
            int ci = (lane >> 4) * 8 + j;
            Wf2[e] = f16_rn(w2[(co * 32 + ci) * 3 + t]);
        }
    } else if (b < 60) {                  // W3: 48 frags x 512 (single fp16)
        int e = (b - 12) * 512 + threadIdx.x;
        #pragma unroll
        for (int r = 0; r < 2; ++r, e += 256) {
            int frag = e >> 9, off = e & 511;
            int lane = off >> 3, j = off & 7;
            int nt = frag & 7, f3 = frag >> 3;
            int ks = f3 & 1, t = f3 >> 1;
            int co = nt * 16 + (lane & 15);
            int ci = ks * 32 + (lane >> 4) * 8 + j;
            Wf3[e] = f16_rn(w3[(co * 64 + ci) * 3 + t]);
        }
    } else {                              // W1: 4 frags x 512 (hi/lo fp16)
        int e = (b - 60) * 512 + threadIdx.x;
        #pragma unroll
        for (int r = 0; r < 2; ++r, e += 256) {
            int frag = e >> 9, off = e & 511;
            int lane = off >> 3, j = off & 7;
            int hl = frag & 1, nt = frag >> 1;
            int co = nt * 16 + (lane & 15);
            int t  = lane >> 4;           // quad = tap (K = t*8+ci)
            float x = (t < 3) ? w1[(co * 8 + j) * 3 + t] : 0.f;
            unsigned short uh, ul; f16_split(x, uh, ul);
            Wf1[e] = hl ? ul : uh;
        }
    }
}

// ===========================================================================
// Fused encoder, all-MFMA convs, fp16 numerics, round 5:
//  - SINGLE-fp16 A-operand for conv2/conv3: B1/X2 stored as one fp16 plane
//    (h only). A-rounding (2^-11 rel) ~= already-accepted W-rounding; adds
//    in quadrature. MFMA/wave 336 -> 192 (-43%); conv2/3 ds_reads halve;
//    epilogue split -> plain cvt; LDS 49.6K -> 28.9K.
//  - conv1 unchanged 3-term (exact input split, hi/lo W1): near-exact
//    first layer, B1 storage rounding dominates its error.
//  - __launch_bounds__(256,4): arch demand now ~55-60 (single W/A frags)
//    vs 64-reg cap; accs 64 AGPR. 4 blocks/CU at 29KB LDS. Tripwire for
//    spills: WRITE_SIZE (must stay 4800).
//  Kept: setprio on MFMA clusters, issue-early W hoists, conv1 input
//  register prefetch, register tail + shuffle L2-norm.
// ===========================================================================
__global__ __launch_bounds__(256, 4) void encoder_fused(
    const float* __restrict__ s_img, const float* __restrict__ q_img,
    const unsigned short* __restrict__ Wf1,
    const float* __restrict__ pb1, const float* __restrict__ pg1,
    const float* __restrict__ pbe1, const float* __restrict__ pm1,
    const float* __restrict__ pv1,
    const float* __restrict__ pb2, const float* __restrict__ pg2,
    const float* __restrict__ pbe2, const float* __restrict__ pm2,
    const float* __restrict__ pv2, const unsigned short* __restrict__ Wf2,
    const float* __restrict__ pb3, const float* __restrict__ pg3,
    const float* __restrict__ pbe3, const float* __restrict__ pm3,
    const float* __restrict__ pv3, const unsigned short* __restrict__ Wf3,
    const float* __restrict__ pwf, const float* __restrict__ pbf,
    const float* __restrict__ pgf, const float* __restrict__ pbef,
    const float* __restrict__ pmf, const float* __restrict__ pvf,
    float* __restrict__ feat_out)
{
    // U regions (time-multiplexed), total 28960 B:
    //  conv1/conv2: B1h @0 (20640), Xth @20640 (4160), Xtl @24800 (4160)
    //  conv3:       X2h @0 (18720)
    //  tail:        part @20640 (1024), featm @21664 (512)  [Xt region, dead]
    __shared__ __align__(16) char U[28960];
    short* const B1h = (short*)U;
    short* const Xth = (short*)(U + 20640);
    short* const Xtl = (short*)(U + 24800);
    short* const X2h = (short*)U;
    float* const part  = (float*)(U + 20640);   // [2][128]
    float* const featm = (float*)(U + 21664);   // [128]
    __shared__ float sc1[32], sh1[32], sc2[64], sh2[64], sc3[128], sh3[128];

    const int tid  = threadIdx.x;
    const int sid  = blockIdx.x;
    const int lane = tid & 63;
    const int wid  = tid >> 6;
    const int mrow = lane & 15;
    const int quad = lane >> 4;
    const int kq   = quad * 8;

    const float* xin = (sid < NSUP) ? (s_img + (size_t)sid * 4096)
                                    : (q_img + (size_t)(sid - NSUP) * 4096);

    // ---- init: fold BN params, zero Xt tail rows + B1 halo rows ----
    if (tid < 32) {
        float s = pg1[tid] * rsqrtf(pv1[tid] + EPS_BN);
        sc1[tid] = s; sh1[tid] = (pb1[tid] - pm1[tid]) * s + pbe1[tid];
    } else if (tid < 96) {
        int c = tid - 32;
        float s = pg2[c] * rsqrtf(pv2[c] + EPS_BN);
        sc2[c] = s; sh2[c] = (pb2[c] - pm2[c]) * s + pbe2[c];
    } else if (tid < 224) {
        int c = tid - 96;
        float s = pg3[c] * rsqrtf(pv3[c] + EPS_BN);
        sc3[c] = s; sh3[c] = (pb3[c] - pm3[c]) * s + pbe3[c];
    }
    if (tid < 8) {   // Xt rows 258,259 (quad-3 overreach): zero, avoid NaN bits
        ((unsigned*)(Xth + 258*8))[tid] = 0;
        ((unsigned*)(Xtl + 258*8))[tid] = 0;
    }
    if (tid < 40) {  // B1 halo rows 0, 257 (epilogues never write them)
        B1h[tid] = 0;
        B1h[257*40 + tid] = 0;
    }
    // preload conv1 W fragments (persist in VGPRs)
    half8 W1h[2], W1l[2];
    #pragma unroll
    for (int nt = 0; nt < 2; ++nt) {
        W1h[nt] = *(const half8*)(Wf1 + ((nt*2 + 0)*512 + lane*8));
        W1l[nt] = *(const half8*)(Wf1 + ((nt*2 + 1)*512 + lane*8));
    }

    // hoisted conv2 tap-0 W fragments (loaded before conv1's final barrier)
    half8 W2t0[4];

    // ---- conv1: 2 halves of 256 pre-pool rows; register input prefetch ----
    float xr[8];
    {
        const int l0 = tid - 1;           // h=0, row tid; l in [-1, 254]
        #pragma unroll
        for (int ci = 0; ci < 8; ++ci)
            xr[ci] = (l0 >= 0) ? xin[ci*512 + l0] : 0.f;
    }
    #pragma unroll
    for (int h = 0; h < 2; ++h) {
        // build Xt row tid from prefetched xr (fp16 exact 2-term split)
        {
            half8 vh, vl;
            #pragma unroll
            for (int ci = 0; ci < 8; ++ci) {
                _Float16 hh = (_Float16)xr[ci];
                float r = xr[ci] - (float)hh;
                vh[ci] = hh; vl[ci] = (_Float16)r;
            }
            *(half8*)&Xth[tid*8] = vh;
            *(half8*)&Xtl[tid*8] = vl;
        }
        if (tid < 2) {                    // rows 256, 257
            const int row = 256 + tid;
            const int l = h*256 + row - 1;    // 255/256 (h=0), 511/512 (h=1)
            half8 vh, vl;
            #pragma unroll
            for (int ci = 0; ci < 8; ++ci) {
                float x = (l < 512) ? xin[ci*512 + l] : 0.f;
                _Float16 hh = (_Float16)x;
                float r = x - (float)hh;
                vh[ci] = hh; vl[ci] = (_Float16)r;
            }
            *(half8*)&Xth[row*8] = vh;
            *(half8*)&Xtl[row*8] = vl;
        }
        __syncthreads();
        if (h == 0) {                     // prefetch half-1 inputs (l in [255,510])
            const int l = 256 + tid - 1;
            #pragma unroll
            for (int ci = 0; ci < 8; ++ci)
                xr[ci] = xin[ci*512 + l];
        }
        // MFMA sweep: wave owns mt_local {4w..4w+3}; A-frag = one b128/row
        #pragma unroll
        for (int mi = 0; mi < 4; ++mi) {
            const int mtl = wid*4 + mi;
            const int mt  = h*16 + mtl;
            const int row = mtl*16 + mrow + quad;
            const half8 Ah = *(const half8*)&Xth[row*8];
            const half8 Al = *(const half8*)&Xtl[row*8];
            floatx4 a1[2] = {};
            __builtin_amdgcn_s_setprio(1);
            #pragma unroll
            for (int nt = 0; nt < 2; ++nt) {
                a1[nt] = __builtin_amdgcn_mfma_f32_16x16x32_f16(Ah, W1h[nt], a1[nt], 0, 0, 0);
                a1[nt] = __builtin_amdgcn_mfma_f32_16x16x32_f16(Ah, W1l[nt], a1[nt], 0, 0, 0);
                a1[nt] = __builtin_amdgcn_mfma_f32_16x16x32_f16(Al, W1h[nt], a1[nt], 0, 0, 0);
            }
            __builtin_amdgcn_s_setprio(0);
            // epilogue: BN+ReLU+pool2 -> B1 rows (single fp16)
            const int pl0 = mt*8 + quad*2 + 1;   // +1 halo
            #pragma unroll
            for (int nt = 0; nt < 2; ++nt) {
                const int co = nt*16 + mrow;
                const float sc = sc1[co], sh = sh1[co];
                floatx4 d = a1[nt];
                float v0 = fmaxf(0.f, fmaxf(d[0]*sc + sh, d[1]*sc + sh));
                float v1 = fmaxf(0.f, fmaxf(d[2]*sc + sh, d[3]*sc + sh));
                B1h[pl0*40 + co]     = (short)f16_rn(v0);
                B1h[(pl0+1)*40 + co] = (short)f16_rn(v1);
            }
        }
        if (h == 1) {   // issue conv2 tap-0 W loads before the barrier
            #pragma unroll
            for (int n = 0; n < 4; ++n)
                W2t0[n] = *(const half8*)(Wf2 + (n*512 + lane*8));
        }
        __syncthreads();   // protect Xt for next half / B1 complete for conv2
    }

    // ---- conv2 MFMA: M=256, N=64, K=32, 3 taps, single-term A*W.
    // Wave w owns mt {4w..4w+3} x ALL nt {0..3}.
    floatx4 acc2[4][4] = {};
    #pragma unroll
    for (int t = 0; t < 3; ++t) {
        half8 W2[4];
        if (t == 0) {
            #pragma unroll
            for (int nt = 0; nt < 4; ++nt) W2[nt] = W2t0[nt];
        } else {
            #pragma unroll
            for (int nt = 0; nt < 4; ++nt)
                W2[nt] = *(const half8*)(Wf2 + ((t*4 + nt)*512 + lane*8));
        }
        #pragma unroll
        for (int mi = 0; mi < 4; ++mi) {
            const int mt = wid*4 + mi;
            const int base = (mt*16 + mrow + t)*40 + kq;
            const half8 Ah = *(const half8*)&B1h[base];
            __builtin_amdgcn_s_setprio(1);
            #pragma unroll
            for (int nt = 0; nt < 4; ++nt)
                acc2[mi][nt] = __builtin_amdgcn_mfma_f32_16x16x32_f16(Ah, W2[nt], acc2[mi][nt], 0, 0, 0);
            __builtin_amdgcn_s_setprio(0);
        }
    }
    __syncthreads();   // B1 dead

    const int mt0 = (wid & 1) * 4;
    const int ntb = (wid >> 1) * 4;

    // ---- conv2 epilogue -> X2 (BN+ReLU+pool2, single fp16) ----
    {
        #pragma unroll
        for (int mi = 0; mi < 4; ++mi) {
            const int mt = wid*4 + mi;
            const int r0 = mt*8 + quad*2 + 1;
            #pragma unroll
            for (int nt = 0; nt < 4; ++nt) {
                const int co = nt*16 + mrow;
                const float sc = sc2[co], sh = sh2[co];
                floatx4 d = acc2[mi][nt];
                float v0 = fmaxf(0.f, fmaxf(d[0]*sc + sh, d[1]*sc + sh));
                float v1 = fmaxf(0.f, fmaxf(d[2]*sc + sh, d[3]*sc + sh));
                X2h[r0*72 + co]     = (short)f16_rn(v0);
                X2h[(r0+1)*72 + co] = (short)f16_rn(v1);
            }
        }
        if (tid < 72) {
            X2h[tid] = 0;
            X2h[129*72 + tid] = 0;
        }
    }
    // issue conv3 (t=0,ks=0) W loads before the barrier
    half8 W3t0[4];
    #pragma unroll
    for (int n = 0; n < 4; ++n)
        W3t0[n] = *(const half8*)(Wf3 + ((ntb + n)*512 + lane*8));
    __syncthreads();

    // ---- conv3 MFMA: M=128, N=128, K=64, 3 taps, single-term.
    // Wave w: mt {(w&1)*4..+3} x nt {(w>>1)*4..+3}.
    floatx4 acc3[4][4] = {};
    #pragma unroll
    for (int t = 0; t < 3; ++t) {
        #pragma unroll
        for (int ks = 0; ks < 2; ++ks) {
            const int fb = (t*2 + ks) * 8;
            half8 W3[4];
            if (t == 0 && ks == 0) {
                #pragma unroll
                for (int n = 0; n < 4; ++n) W3[n] = W3t0[n];
            } else {
                #pragma unroll
                for (int n = 0; n < 4; ++n)
                    W3[n] = *(const half8*)(Wf3 + ((fb + ntb + n)*512 + lane*8));
            }
            #pragma unroll
            for (int mi = 0; mi < 4; ++mi) {
                const int base = ((mt0 + mi)*16 + mrow + t)*72 + ks*32 + kq;
                const half8 Ah = *(const half8*)&X2h[base];
                __builtin_amdgcn_s_setprio(1);
                #pragma unroll
                for (int n = 0; n < 4; ++n)
                    acc3[mi][n] = __builtin_amdgcn_mfma_f32_16x16x32_f16(Ah, W3[n], acc3[mi][n], 0, 0, 0);
                __builtin_amdgcn_s_setprio(0);
            }
        }
    }
    __syncthreads();   // X2 reads done; tail arrays live in Xt region

    // ---- conv3 epilogue: BN+ReLU+pool2+mean, 2-wave partial reduction ----
    float s4[4];
    {
        #pragma unroll
        for (int n = 0; n < 4; ++n) {
            const int co = (ntb + n)*16 + mrow;
            const float sc = sc3[co], sh = sh3[co];
            float s = 0.f;
            #pragma unroll
            for (int mi = 0; mi < 4; ++mi) {
                floatx4 d = acc3[mi][n];
                s += fmaxf(0.f, fmaxf(d[0]*sc + sh, d[1]*sc + sh));
                s += fmaxf(0.f, fmaxf(d[2]*sc + sh, d[3]*sc + sh));
            }
            s4[n] = s;
        }
        #pragma unroll
        for (int n = 0; n < 4; ++n) {
            s4[n] += __shfl_xor(s4[n], 16);
            s4[n] += __shfl_xor(s4[n], 32);
        }
        if (lane < 16) {
            #pragma unroll
            for (int n = 0; n < 4; ++n)
                part[(wid & 1)*128 + (ntb + n)*16 + lane] = s4[n];
        }
    }
    __syncthreads();
    if (tid < 128) featm[tid] = (part[tid] + part[128 + tid]) * (1.0f / 64.0f);
    __syncthreads();

    // ---- linear 128->128 + BN + ReLU (register result) + L2 normalize ----
    float vout = 0.f;
    if (tid < 128) {
        const float* wr = pwf + (size_t)tid * 128;
        float s = 0.f;
        #pragma unroll 4
        for (int i = 0; i < 128; i += 4) {
            float4 w4 = *(const float4*)(wr + i);
            s += w4.x*featm[i] + w4.y*featm[i+1] + w4.z*featm[i+2] + w4.w*featm[i+3];
        }
        s += pbf[tid];
        s = (s - pmf[tid]) * (pgf[tid] * rsqrtf(pvf[tid] + EPS_BN)) + pbef[tid];
        vout = fmaxf(s, 0.f);
        float ss = vout * vout;
        ss += __shfl_xor(ss, 1);
        ss += __shfl_xor(ss, 2);
        ss += __shfl_xor(ss, 4);
        ss += __shfl_xor(ss, 8);
        ss += __shfl_xor(ss, 16);
        ss += __shfl_xor(ss, 32);
        if (lane == 0) part[wid] = ss;   // wid 0,1
    }
    __syncthreads();
    if (tid < 128) {
        float n = fmaxf(sqrtf(part[0] + part[1]), 1e-12f);
        feat_out[(size_t)sid * 128 + tid] = vout / n;
    }
}

// ---------------------------------------------------------------------------
// proto: stage labels in LDS, unconditional coalesced feature loads with
// predicated accumulate (no 200-deep dependent global-load chain).
__global__ __launch_bounds__(128) void proto_kernel(
    const float* __restrict__ feat_s, const int* __restrict__ s_lab,
    float* __restrict__ protos)
{
    __shared__ int labL[NSHOTB];
    const int b = blockIdx.x / NWAY;
    const int w = blockIdx.x % NWAY;
    const int f = threadIdx.x;
    const int* lab = s_lab + b * NSHOTB;
    for (int s = f; s < NSHOTB; s += 128) labL[s] = lab[s];
    __syncthreads();
    const float* sf = feat_s + (size_t)b * NSHOTB * 128;
    float acc = 0.f;
    int cnt = 0;
    #pragma unroll 4
    for (int s = 0; s < NSHOTB; ++s) {
        float x = sf[s*128 + f];
        bool m = (labL[s] == w);
        acc += m ? x : 0.f;
        cnt += m ? 1 : 0;
    }
    protos[(size_t)blockIdx.x * 128 + f] = acc / (float)cnt;
}

__global__ __launch_bounds__(256) void dist_kernel(
    const float* __restrict__ feat_q, const float* __restrict__ protos,
    float* __restrict__ out)
{
    int idx = blockIdx.x * 256 + threadIdx.x;
    if (idx >= 32 * NQB * NWAY) return;
    int b = idx / (NQB * NWAY);
    int r = idx - b * (NQB * NWAY);
    int q = r / NWAY;
    int w = r - q * NWAY;
    const float* qf = feat_q + (size_t)(b * NQB + q) * 128;
    const float* pp = protos + (size_t)(b * NWAY + w) * 128;
    float d2 = 0.f;
    #pragma unroll 4
    for (int i = 0; i < 128; ++i) { float d = qf[i] - pp[i]; d2 += d * d; }
    out[idx] = -sqrtf(fmaxf(d2, 0.f));
}

// ---------------------------------------------------------------------------
extern "C" void kernel_launch(void* const* d_in, const int* in_sizes, int n_in,
                              void* d_out, int out_size, void* d_ws, size_t ws_size,
                              hipStream_t stream) {
    const float* s_img = (const float*)d_in[0];
    const float* q_img = (const float*)d_in[1];
    const int*   s_lab = (const int*)d_in[2];
    const float* pw1  = (const float*)d_in[3];
    const float* pb1  = (const float*)d_in[4];
    const float* pg1  = (const float*)d_in[5];
    const float* pbe1 = (const float*)d_in[6];
    const float* pm1  = (const float*)d_in[7];
    const float* pv1  = (const float*)d_in[8];
    const float* pw2  = (const float*)d_in[9];
    const float* pb2  = (const float*)d_in[10];
    const float* pg2  = (const float*)d_in[11];
    const float* pbe2 = (const float*)d_in[12];
    const float* pm2  = (const float*)d_in[13];
    const float* pv2  = (const float*)d_in[14];
    const float* pw3  = (const float*)d_in[15];
    const float* pb3  = (const float*)d_in[16];
    const float* pg3  = (const float*)d_in[17];
    const float* pbe3 = (const float*)d_in[18];
    const float* pm3  = (const float*)d_in[19];
    const float* pv3  = (const float*)d_in[20];
    const float* pwf  = (const float*)d_in[21];
    const float* pbf  = (const float*)d_in[22];
    const float* pgf  = (const float*)d_in[23];
    const float* pbef = (const float*)d_in[24];
    const float* pmf  = (const float*)d_in[25];
    const float* pvf  = (const float*)d_in[26];

    const size_t feat_elems = (size_t)NSAMP * 128;      // fp32
    const size_t prot_elems = (size_t)32 * NWAY * 128;  // fp32
    float* feat   = (float*)d_ws;
    float* protos = feat + feat_elems;
    unsigned short* Wf1 = (unsigned short*)(protos + prot_elems);
    unsigned short* Wf2 = Wf1 + 2048;    // W1: 4 frags x 512 (h/l)
    unsigned short* Wf3 = Wf2 + 6144;    // W2: 12 frags x 512; W3: 48 x 512
    float* out = (float*)d_out;

    prep_weights<<<64, 256, 0, stream>>>(pw1, pw2, pw3, Wf1, Wf2, Wf3);

    encoder_fused<<<NSAMP, 256, 0, stream>>>(
        s_img, q_img,
        Wf1, pb1, pg1, pbe1, pm1, pv1,
        pb2, pg2, pbe2, pm2, pv2, Wf2,
        pb3, pg3, pbe3, pm3, pv3, Wf3,
        pwf, pbf, pgf, pbef, pmf, pvf,
        feat);

    proto_kernel<<<32 * NWAY, 128, 0, stream>>>(feat, s_lab, protos);

    dist_kernel<<<(32 * NQB * NWAY + 255) / 256, 256, 0, stream>>>(
        feat + (size_t)NSUP * 128, protos, out);
}

// Round 6
// 383.034 us; speedup vs baseline: 1.5767x; 1.0111x over previous
//
#include <hip/hip_runtime.h>
#include <hip/hip_fp16.h>
#include <math.h>

#define EPS_BN 1e-5f

// Problem constants: B=32, NS=200, NQ=100, C=8, L=512, H=32, F=128, N_WAY=20
#define NSUP   6400
#define NQRY   3200
#define NSAMP  9600
#define NWAY   20
#define NSHOTB 200
#define NQB    100

using short8  = __attribute__((ext_vector_type(8))) short;
using half8   = __attribute__((ext_vector_type(8))) _Float16;
using floatx4 = __attribute__((ext_vector_type(4))) float;

// fp16 split: hi = RNE(x), lo = RNE(x - hi). Residual x-hi is EXACT in f32
// (Sterbenz), so 2-term error ~2^-21.
__device__ __forceinline__ void f16_split(float x, unsigned short& uh, unsigned short& ul) {
    _Float16 hh = (_Float16)x;
    float r = x - (float)hh;
    _Float16 hl = (_Float16)r;
    uh = __builtin_bit_cast(unsigned short, hh);
    ul = __builtin_bit_cast(unsigned short, hl);
}
__device__ __forceinline__ unsigned short f16_rn(float x) {
    _Float16 h = (_Float16)x;
    return __builtin_bit_cast(unsigned short, h);
}

// ===========================================================================
// prep: W1 [32][8][3], W2 [64][32][3], W3 [128][64][3] -> MFMA B-fragment
// order (layouts verified earlier; dtype-independent).
// W2/W3 single fp16 fragment; W1 hi/lo pair (conv1 stays 3-term).
//  W1: frag=nt*2+hl; co=nt*16+(lane&15), k=quad*8+j -> t=quad, ci=j; t==3 -> 0
// ===========================================================================
__global__ __launch_bounds__(256) void prep_weights(
    const float* __restrict__ w1, const float* __restrict__ w2,
    const float* __restrict__ w3, unsigned short* __restrict__ Wf1,
    unsigned short* __restrict__ Wf2, unsigned short* __restrict__ Wf3)
{
    int b = blockIdx.x;
    if (b < 12) {                         // W2: 12 frags x 512 (single fp16)
        int e = b * 512 + threadIdx.x;
        #pragma unroll
        for (int r = 0; r < 2; ++r, e += 256) {
            int frag = e >> 9, off = e & 511;
            int lane = off >> 3, j = off & 7;
            int nt = frag & 3, t = frag >> 2;
            int co = nt * 16 + (lane & 15);
            int ci = (lane >> 4) * 8 + j;
            Wf2[e] = f16_rn(w2[(co * 32 + ci) * 3 + t]);
        }
    } else if (b < 60) {                  // W3: 48 frags x 512 (single fp16)
        int e = (b - 12) * 512 + threadIdx.x;
        #pragma unroll
        for (int r = 0; r < 2; ++r, e += 256) {
            int frag = e >> 9, off = e & 511;
            int lane = off >> 3, j = off & 7;
            int nt = frag & 7, f3 = frag >> 3;
            int ks = f3 & 1, t = f3 >> 1;
            int co = nt * 16 + (lane & 15);
            int ci = ks * 32 + (lane >> 4) * 8 + j;
            Wf3[e] = f16_rn(w3[(co * 64 + ci) * 3 + t]);
        }
    } else {                              // W1: 4 frags x 512 (hi/lo fp16)
        int e = (b - 60) * 512 + threadIdx.x;
        #pragma unroll
        for (int r = 0; r < 2; ++r, e += 256) {
            int frag = e >> 9, off = e & 511;
            int lane = off >> 3, j = off & 7;
            int hl = frag & 1, nt = frag >> 1;
            int co = nt * 16 + (lane & 15);
            int t  = lane >> 4;           // quad = tap (K = t*8+ci)
            float x = (t < 3) ? w1[(co * 8 + j) * 3 + t] : 0.f;
            unsigned short uh, ul; f16_split(x, uh, ul);
            Wf1[e] = hl ? ul : uh;
        }
    }
}

// ===========================================================================
// Fused encoder, round 6: BARRIER-FREE CONV1.
// Round-5 counters: MfmaUtil 25 / VALUBusy 33 / ~42% dual-idle -> latency
// and barrier bound, not pipe bound. conv1's 4 barriers re-lockstepped the
// block's waves around Xt even though each wave reads rows its own lanes
// can build. New conv1: full-length Xt (516 rows, fits with single-plane
// B1); wave w builds rows 128w..128w+127 (lane ln -> rows 2ln,2ln+1) plus
// 3 halo rows 128w+128..130 (lanes 0-2; adjacent waves write identical
// bits -> benign race); then sweeps its 8 mt tiles in one 48-MFMA run.
// conv1 barriers 4 -> 1; waves drift -> within-block phase diversity.
// Numerics BIT-IDENTICAL to round 5 (same splits, same MFMA order):
// absmax must stay 0.0004882812 exactly.
// ===========================================================================
__global__ __launch_bounds__(256, 4) void encoder_fused(
    const float* __restrict__ s_img, const float* __restrict__ q_img,
    const unsigned short* __restrict__ Wf1,
    const float* __restrict__ pb1, const float* __restrict__ pg1,
    const float* __restrict__ pbe1, const float* __restrict__ pm1,
    const float* __restrict__ pv1,
    const float* __restrict__ pb2, const float* __restrict__ pg2,
    const float* __restrict__ pbe2, const float* __restrict__ pm2,
    const float* __restrict__ pv2, const unsigned short* __restrict__ Wf2,
    const float* __restrict__ pb3, const float* __restrict__ pg3,
    const float* __restrict__ pbe3, const float* __restrict__ pm3,
    const float* __restrict__ pv3, const unsigned short* __restrict__ Wf3,
    const float* __restrict__ pwf, const float* __restrict__ pbf,
    const float* __restrict__ pgf, const float* __restrict__ pbef,
    const float* __restrict__ pmf, const float* __restrict__ pvf,
    float* __restrict__ feat_out)
{
    // U regions (time-multiplexed), total 37152 B:
    //  conv1/conv2: B1h @0 (20640), Xth @20640 (8256 = 516 rows x 16B),
    //               Xtl @28896 (8256)
    //  conv3:       X2h @0 (18720)
    //  tail:        part @20640 (1024), featm @21664 (512)  [Xt dead]
    __shared__ __align__(16) char U[37152];
    short* const B1h = (short*)U;
    short* const Xth = (short*)(U + 20640);
    short* const Xtl = (short*)(U + 28896);
    short* const X2h = (short*)U;
    float* const part  = (float*)(U + 20640);   // [2][128]
    float* const featm = (float*)(U + 21664);   // [128]
    __shared__ float sc1[32], sh1[32], sc2[64], sh2[64], sc3[128], sh3[128];

    const int tid  = threadIdx.x;
    const int sid  = blockIdx.x;
    const int lane = tid & 63;
    const int wid  = tid >> 6;
    const int mrow = lane & 15;
    const int quad = lane >> 4;
    const int kq   = quad * 8;

    const float* xin = (sid < NSUP) ? (s_img + (size_t)sid * 4096)
                                    : (q_img + (size_t)(sid - NSUP) * 4096);

    // ---- init: fold BN params, zero B1 halo rows ----
    if (tid < 32) {
        float s = pg1[tid] * rsqrtf(pv1[tid] + EPS_BN);
        sc1[tid] = s; sh1[tid] = (pb1[tid] - pm1[tid]) * s + pbe1[tid];
    } else if (tid < 96) {
        int c = tid - 32;
        float s = pg2[c] * rsqrtf(pv2[c] + EPS_BN);
        sc2[c] = s; sh2[c] = (pb2[c] - pm2[c]) * s + pbe2[c];
    } else if (tid < 224) {
        int c = tid - 96;
        float s = pg3[c] * rsqrtf(pv3[c] + EPS_BN);
        sc3[c] = s; sh3[c] = (pb3[c] - pm3[c]) * s + pbe3[c];
    }
    if (tid < 40) {  // B1 halo rows 0, 257 (epilogues never write them)
        B1h[tid] = 0;
        B1h[257*40 + tid] = 0;
    }
    // preload conv1 W fragments (persist in VGPRs)
    half8 W1h[2], W1l[2];
    #pragma unroll
    for (int nt = 0; nt < 2; ++nt) {
        W1h[nt] = *(const half8*)(Wf1 + ((nt*2 + 0)*512 + lane*8));
        W1l[nt] = *(const half8*)(Wf1 + ((nt*2 + 1)*512 + lane*8));
    }

    // ---- conv1: barrier-free. Wave w builds Xt rows 128w..128w+127
    // (lane ln -> rows 2ln, 2ln+1; Xt row r holds x[*][r-1]) plus halo
    // rows 128w+128..+130 (lanes 0-2; overlapping writes are bit-identical).
    // Compiler inserts lgkmcnt before the same-wave cross-lane reads.
    #pragma unroll
    for (int r2 = 0; r2 < 2; ++r2) {
        const int row = 2*tid + r2;
        const int l = row - 1;            // l in [-1, 510]; l<0 -> 0
        half8 vh, vl;
        #pragma unroll
        for (int ci = 0; ci < 8; ++ci) {
            float x = (l >= 0) ? xin[ci*512 + l] : 0.f;
            _Float16 hh = (_Float16)x;
            float r = x - (float)hh;
            vh[ci] = hh; vl[ci] = (_Float16)r;
        }
        *(half8*)&Xth[row*8] = vh;
        *(half8*)&Xtl[row*8] = vl;
    }
    if (lane < 3) {                       // halo rows 128w+128..130
        const int row = 128*wid + 128 + lane;
        const int l = row - 1;            // may be >= 512 (zero)
        half8 vh, vl;
        #pragma unroll
        for (int ci = 0; ci < 8; ++ci) {
            float x = (l < 512) ? xin[ci*512 + l] : 0.f;
            _Float16 hh = (_Float16)x;
            float r = x - (float)hh;
            vh[ci] = hh; vl[ci] = (_Float16)r;
        }
        *(half8*)&Xth[row*8] = vh;
        *(half8*)&Xtl[row*8] = vl;
    }
    // MFMA sweep: wave owns mt {8w..8w+7}; reads only rows 128w..128w+130.
    #pragma unroll
    for (int mi = 0; mi < 8; ++mi) {
        const int mt  = wid*8 + mi;
        const int row = mt*16 + mrow + quad;
        const half8 Ah = *(const half8*)&Xth[row*8];
        const half8 Al = *(const half8*)&Xtl[row*8];
        floatx4 a1[2] = {};
        __builtin_amdgcn_s_setprio(1);
        #pragma unroll
        for (int nt = 0; nt < 2; ++nt) {
            a1[nt] = __builtin_amdgcn_mfma_f32_16x16x32_f16(Ah, W1h[nt], a1[nt], 0, 0, 0);
            a1[nt] = __builtin_amdgcn_mfma_f32_16x16x32_f16(Ah, W1l[nt], a1[nt], 0, 0, 0);
            a1[nt] = __builtin_amdgcn_mfma_f32_16x16x32_f16(Al, W1h[nt], a1[nt], 0, 0, 0);
        }
        __builtin_amdgcn_s_setprio(0);
        // epilogue: BN+ReLU+pool2 -> B1 rows (single fp16)
        const int pl0 = mt*8 + quad*2 + 1;   // +1 halo
        #pragma unroll
        for (int nt = 0; nt < 2; ++nt) {
            const int co = nt*16 + mrow;
            const float sc = sc1[co], sh = sh1[co];
            floatx4 d = a1[nt];
            float v0 = fmaxf(0.f, fmaxf(d[0]*sc + sh, d[1]*sc + sh));
            float v1 = fmaxf(0.f, fmaxf(d[2]*sc + sh, d[3]*sc + sh));
            B1h[pl0*40 + co]     = (short)f16_rn(v0);
            B1h[(pl0+1)*40 + co] = (short)f16_rn(v1);
        }
    }
    // issue conv2 tap-0 W loads before the barrier
    half8 W2t0[4];
    #pragma unroll
    for (int n = 0; n < 4; ++n)
        W2t0[n] = *(const half8*)(Wf2 + (n*512 + lane*8));
    __syncthreads();   // B1 complete (conv2 reads 2 halo rows from neighbors)

    // ---- conv2 MFMA: M=256, N=64, K=32, 3 taps, single-term A*W.
    // Wave w owns mt {4w..4w+3} x ALL nt {0..3}.
    floatx4 acc2[4][4] = {};
    #pragma unroll
    for (int t = 0; t < 3; ++t) {
        half8 W2[4];
        if (t == 0) {
            #pragma unroll
            for (int nt = 0; nt < 4; ++nt) W2[nt] = W2t0[nt];
        } else {
            #pragma unroll
            for (int nt = 0; nt < 4; ++nt)
                W2[nt] = *(const half8*)(Wf2 + ((t*4 + nt)*512 + lane*8));
        }
        #pragma unroll
        for (int mi = 0; mi < 4; ++mi) {
            const int mt = wid*4 + mi;
            const int base = (mt*16 + mrow + t)*40 + kq;
            const half8 Ah = *(const half8*)&B1h[base];
            __builtin_amdgcn_s_setprio(1);
            #pragma unroll
            for (int nt = 0; nt < 4; ++nt)
                acc2[mi][nt] = __builtin_amdgcn_mfma_f32_16x16x32_f16(Ah, W2[nt], acc2[mi][nt], 0, 0, 0);
            __builtin_amdgcn_s_setprio(0);
        }
    }
    __syncthreads();   // B1 dead

    const int mt0 = (wid & 1) * 4;
    const int ntb = (wid >> 1) * 4;

    // ---- conv2 epilogue -> X2 (BN+ReLU+pool2, single fp16) ----
    {
        #pragma unroll
        for (int mi = 0; mi < 4; ++mi) {
            const int mt = wid*4 + mi;
            const int r0 = mt*8 + quad*2 + 1;
            #pragma unroll
            for (int nt = 0; nt < 4; ++nt) {
                const int co = nt*16 + mrow;
                const float sc = sc2[co], sh = sh2[co];
                floatx4 d = acc2[mi][nt];
                float v0 = fmaxf(0.f, fmaxf(d[0]*sc + sh, d[1]*sc + sh));
                float v1 = fmaxf(0.f, fmaxf(d[2]*sc + sh, d[3]*sc + sh));
                X2h[r0*72 + co]     = (short)f16_rn(v0);
                X2h[(r0+1)*72 + co] = (short)f16_rn(v1);
            }
        }
        if (tid < 72) {
            X2h[tid] = 0;
            X2h[129*72 + tid] = 0;
        }
    }
    // issue conv3 (t=0,ks=0) W loads before the barrier
    half8 W3t0[4];
    #pragma unroll
    for (int n = 0; n < 4; ++n)
        W3t0[n] = *(const half8*)(Wf3 + ((ntb + n)*512 + lane*8));
    __syncthreads();

    // ---- conv3 MFMA: M=128, N=128, K=64, 3 taps, single-term.
    // Wave w: mt {(w&1)*4..+3} x nt {(w>>1)*4..+3}.
    floatx4 acc3[4][4] = {};
    #pragma unroll
    for (int t = 0; t < 3; ++t) {
        #pragma unroll
        for (int ks = 0; ks < 2; ++ks) {
            const int fb = (t*2 + ks) * 8;
            half8 W3[4];
            if (t == 0 && ks == 0) {
                #pragma unroll
                for (int n = 0; n < 4; ++n) W3[n] = W3t0[n];
            } else {
                #pragma unroll
                for (int n = 0; n < 4; ++n)
                    W3[n] = *(const half8*)(Wf3 + ((fb + ntb + n)*512 + lane*8));
            }
            #pragma unroll
            for (int mi = 0; mi < 4; ++mi) {
                const int base = ((mt0 + mi)*16 + mrow + t)*72 + ks*32 + kq;
                const half8 Ah = *(const half8*)&X2h[base];
                __builtin_amdgcn_s_setprio(1);
                #pragma unroll
                for (int n = 0; n < 4; ++n)
                    acc3[mi][n] = __builtin_amdgcn_mfma_f32_16x16x32_f16(Ah, W3[n], acc3[mi][n], 0, 0, 0);
                __builtin_amdgcn_s_setprio(0);
            }
        }
    }
    __syncthreads();   // X2 reads done; tail arrays live in Xt region

    // ---- conv3 epilogue: BN+ReLU+pool2+mean, 2-wave partial reduction ----
    float s4[4];
    {
        #pragma unroll
        for (int n = 0; n < 4; ++n) {
            const int co = (ntb + n)*16 + mrow;
            const float sc = sc3[co], sh = sh3[co];
            float s = 0.f;
            #pragma unroll
            for (int mi = 0; mi < 4; ++mi) {
                floatx4 d = acc3[mi][n];
                s += fmaxf(0.f, fmaxf(d[0]*sc + sh, d[1]*sc + sh));
                s += fmaxf(0.f, fmaxf(d[2]*sc + sh, d[3]*sc + sh));
            }
            s4[n] = s;
        }
        #pragma unroll
        for (int n = 0; n < 4; ++n) {
            s4[n] += __shfl_xor(s4[n], 16);
            s4[n] += __shfl_xor(s4[n], 32);
        }
        if (lane < 16) {
            #pragma unroll
            for (int n = 0; n < 4; ++n)
                part[(wid & 1)*128 + (ntb + n)*16 + lane] = s4[n];
        }
    }
    __syncthreads();
    if (tid < 128) featm[tid] = (part[tid] + part[128 + tid]) * (1.0f / 64.0f);
    __syncthreads();

    // ---- linear 128->128 + BN + ReLU (register result) + L2 normalize ----
    float vout = 0.f;
    if (tid < 128) {
        const float* wr = pwf + (size_t)tid * 128;
        float s = 0.f;
        #pragma unroll 4
        for (int i = 0; i < 128; i += 4) {
            float4 w4 = *(const float4*)(wr + i);
            s += w4.x*featm[i] + w4.y*featm[i+1] + w4.z*featm[i+2] + w4.w*featm[i+3];
        }
        s += pbf[tid];
        s = (s - pmf[tid]) * (pgf[tid] * rsqrtf(pvf[tid] + EPS_BN)) + pbef[tid];
        vout = fmaxf(s, 0.f);
        float ss = vout * vout;
        ss += __shfl_xor(ss, 1);
        ss += __shfl_xor(ss, 2);
        ss += __shfl_xor(ss, 4);
        ss += __shfl_xor(ss, 8);
        ss += __shfl_xor(ss, 16);
        ss += __shfl_xor(ss, 32);
        if (lane == 0) part[wid] = ss;   // wid 0,1
    }
    __syncthreads();
    if (tid < 128) {
        float n = fmaxf(sqrtf(part[0] + part[1]), 1e-12f);
        feat_out[(size_t)sid * 128 + tid] = vout / n;
    }
}

// ---------------------------------------------------------------------------
// proto: stage labels in LDS, unconditional coalesced feature loads with
// predicated accumulate (no 200-deep dependent global-load chain).
__global__ __launch_bounds__(128) void proto_kernel(
    const float* __restrict__ feat_s, const int* __restrict__ s_lab,
    float* __restrict__ protos)
{
    __shared__ int labL[NSHOTB];
    const int b = blockIdx.x / NWAY;
    const int w = blockIdx.x % NWAY;
    const int f = threadIdx.x;
    const int* lab = s_lab + b * NSHOTB;
    for (int s = f; s < NSHOTB; s += 128) labL[s] = lab[s];
    __syncthreads();
    const float* sf = feat_s + (size_t)b * NSHOTB * 128;
    float acc = 0.f;
    int cnt = 0;
    #pragma unroll 4
    for (int s = 0; s < NSHOTB; ++s) {
        float x = sf[s*128 + f];
        bool m = (labL[s] == w);
        acc += m ? x : 0.f;
        cnt += m ? 1 : 0;
    }
    protos[(size_t)blockIdx.x * 128 + f] = acc / (float)cnt;
}

__global__ __launch_bounds__(256) void dist_kernel(
    const float* __restrict__ feat_q, const float* __restrict__ protos,
    float* __restrict__ out)
{
    int idx = blockIdx.x * 256 + threadIdx.x;
    if (idx >= 32 * NQB * NWAY) return;
    int b = idx / (NQB * NWAY);
    int r = idx - b * (NQB * NWAY);
    int q = r / NWAY;
    int w = r - q * NWAY;
    const float* qf = feat_q + (size_t)(b * NQB + q) * 128;
    const float* pp = protos + (size_t)(b * NWAY + w) * 128;
    float d2 = 0.f;
    #pragma unroll 4
    for (int i = 0; i < 128; ++i) { float d = qf[i] - pp[i]; d2 += d * d; }
    out[idx] = -sqrtf(fmaxf(d2, 0.f));
}

// ---------------------------------------------------------------------------
extern "C" void kernel_launch(void* const* d_in, const int* in_sizes, int n_in,
                              void* d_out, int out_size, void* d_ws, size_t ws_size,
                              hipStream_t stream) {
    const float* s_img = (const float*)d_in[0];
    const float* q_img = (const float*)d_in[1];
    const int*   s_lab = (const int*)d_in[2];
    const float* pw1  = (const float*)d_in[3];
    const float* pb1  = (const float*)d_in[4];
    const float* pg1  = (const float*)d_in[5];
    const float* pbe1 = (const float*)d_in[6];
    const float* pm1  = (const float*)d_in[7];
    const float* pv1  = (const float*)d_in[8];
    const float* pw2  = (const float*)d_in[9];
    const float* pb2  = (const float*)d_in[10];
    const float* pg2  = (const float*)d_in[11];
    const float* pbe2 = (const float*)d_in[12];
    const float* pm2  = (const float*)d_in[13];
    const float* pv2  = (const float*)d_in[14];
    const float* pw3  = (const float*)d_in[15];
    const float* pb3  = (const float*)d_in[16];
    const float* pg3  = (const float*)d_in[17];
    const float* pbe3 = (const float*)d_in[18];
    const float* pm3  = (const float*)d_in[19];
    const float* pv3  = (const float*)d_in[20];
    const float* pwf  = (const float*)d_in[21];
    const float* pbf  = (const float*)d_in[22];
    const float* pgf  = (const float*)d_in[23];
    const float* pbef = (const float*)d_in[24];
    const float* pmf  = (const float*)d_in[25];
    const float* pvf  = (const float*)d_in[26];

    const size_t feat_elems = (size_t)NSAMP * 128;      // fp32
    const size_t prot_elems = (size_t)32 * NWAY * 128;  // fp32
    float* feat   = (float*)d_ws;
    float* protos = feat + feat_elems;
    unsigned short* Wf1 = (unsigned short*)(protos + prot_elems);
    unsigned short* Wf2 = Wf1 + 2048;    // W1: 4 frags x 512 (h/l)
    unsigned short* Wf3 = Wf2 + 6144;    // W2: 12 frags x 512; W3: 48 x 512
    float* out = (float*)d_out;

    prep_weights<<<64, 256, 0, stream>>>(pw1, pw2, pw3, Wf1, Wf2, Wf3);

    encoder_fused<<<NSAMP, 256, 0, stream>>>(
        s_img, q_img,
        Wf1, pb1, pg1, pbe1, pm1, pv1,
        pb2, pg2, pbe2, pm2, pv2, Wf2,
        pb3, pg3, pbe3, pm3, pv3, Wf3,
        pwf, pbf, pgf, pbef, pmf, pvf,
        feat);

    proto_kernel<<<32 * NWAY, 128, 0, stream>>>(feat, s_lab, protos);

    dist_kernel<<<(32 * NQB * NWAY + 255) / 256, 256, 0, stream>>>(
        feat + (size_t)NSUP * 128, protos, out);
}